// Round 6
// baseline (1382.581 us; speedup 1.0000x reference)
//
#include <hip/hip_runtime.h>

#define NN   32768
#define NPG  4096
#define NGR  8
#define NE   524288
#define NEGS 0.2f

typedef float  v4f __attribute__((ext_vector_type(4)));
typedef short  v8s __attribute__((ext_vector_type(8)));

__device__ __forceinline__ float lrelu(float x){ return x > 0.f ? x : NEGS*x; }

// round-to-nearest-even fp32 -> bf16 (bit trick; inputs are finite)
__device__ __forceinline__ unsigned short f2bf(float v){
  unsigned int u = __float_as_uint(v);
  u = u + 0x7fffu + ((u >> 16) & 1u);
  return (unsigned short)(u >> 16);
}
__device__ __forceinline__ float bf2f(unsigned short s){
  return __uint_as_float(((unsigned int)s) << 16);
}

// ---------------- GAT1 node transforms (in-dim 5) ----------------
__global__ __launch_bounds__(256) void k_xform5(
    const float* __restrict__ x,
    const float* __restrict__ wl, const float* __restrict__ bl,
    const float* __restrict__ wr, const float* __restrict__ br,
    float* __restrict__ xl, float* __restrict__ xr) {
  int t = blockIdx.x * 256 + threadIdx.x;          // NN*128 threads
  int n = t >> 7, oc = t & 127;
  const float* xp = x + n * 5;
  float a = bl[oc], b = br[oc];
  #pragma unroll
  for (int j = 0; j < 5; ++j) {
    float v = xp[j];
    a += v * wl[j * 128 + oc];
    b += v * wr[j * 128 + oc];
  }
  xl[t] = a; xr[t] = b;
}

// ---------------- CSR build (bucket edges by dst) ----------------
__global__ __launch_bounds__(256) void k_count(const int* __restrict__ dst, int* __restrict__ cnt) {
  int e = blockIdx.x * 256 + threadIdx.x;
  atomicAdd(&cnt[dst[e]], 1);
}

__global__ __launch_bounds__(1024) void k_scan(const int* __restrict__ cnt,
                                               int* __restrict__ start, int* __restrict__ cur) {
  __shared__ int sh[1024];
  int t = threadIdx.x;
  int base = t * 32;
  int s = 0;
  for (int i = 0; i < 32; ++i) s += cnt[base + i];
  sh[t] = s;
  __syncthreads();
  for (int ofs = 1; ofs < 1024; ofs <<= 1) {
    int v = (t >= ofs) ? sh[t - ofs] : 0;
    __syncthreads();
    sh[t] += v;
    __syncthreads();
  }
  int run = sh[t] - s;                              // exclusive prefix
  for (int i = 0; i < 32; ++i) {
    start[base + i] = run; cur[base + i] = run;
    run += cnt[base + i];
  }
}

__global__ __launch_bounds__(256) void k_scatter(const int* __restrict__ dst,
                                                 const int* __restrict__ srcv,
                                                 int* __restrict__ cur,
                                                 int* __restrict__ bkt_e, int* __restrict__ bkt_s) {
  int e = blockIdx.x * 256 + threadIdx.x;
  int p = atomicAdd(&cur[dst[e]], 1);
  bkt_e[p] = e;
  bkt_s[p] = srcv[e];
}

// ---------------- GATv2 edge pass: one wave per dst node, online softmax,
// software-pipelined gathers (idx prefetch 2-deep, data prefetch 1-deep) ----------------
template<int HAS_EA>
__global__ __launch_bounds__(256) void k_gat_edge(
    const float* __restrict__ xl, const float* __restrict__ xr,
    const float* __restrict__ ea,
    const float* __restrict__ we, const float* __restrict__ att,
    const float* __restrict__ bias,
    const int* __restrict__ start, const int* __restrict__ cnt,
    const int* __restrict__ bsrc, const int* __restrict__ bedge,
    float* __restrict__ out) {
  int wv = threadIdx.x >> 6, lane = threadIdx.x & 63;
  int n = blockIdx.x * 4 + wv;
  int s0 = start[n], deg = cnt[n];
  float xr0 = xr[n * 128 + lane], xr1 = xr[n * 128 + 64 + lane];
  float a0 = att[lane], a1 = att[64 + lane];
  float w0r[6], w1r[6];
  if (HAS_EA) {
    #pragma unroll
    for (int j = 0; j < 6; ++j) { w0r[j] = we[j * 128 + lane]; w1r[j] = we[j * 128 + 64 + lane]; }
  }
  float m0 = -1e30f, m1 = -1e30f, d0 = 0.f, d1 = 0.f, o0 = 0.f, o1 = 0.f;

  float l0 = 0.f, l1 = 0.f, ecur[6], enxt[6];
  int sNxt = 0;
  if (deg > 0) {
    int sCur = bsrc[s0];
    l0 = xl[sCur * 128 + lane]; l1 = xl[sCur * 128 + 64 + lane];
    if (HAS_EA) {
      int e = bedge[s0];
      #pragma unroll
      for (int j = 0; j < 6; ++j) ecur[j] = ea[e * 6 + j];
    }
    if (deg > 1) sNxt = bsrc[s0 + 1];
  }

  for (int i = 0; i < deg; ++i) {
    float l0c = l0, l1c = l1;
    // issue next edge's gathers before computing this edge
    if (i + 1 < deg) {
      l0 = xl[sNxt * 128 + lane]; l1 = xl[sNxt * 128 + 64 + lane];
      if (HAS_EA) {
        int e = bedge[s0 + i + 1];
        #pragma unroll
        for (int j = 0; j < 6; ++j) enxt[j] = ea[e * 6 + j];
      }
    }
    int sNN = (i + 2 < deg) ? bsrc[s0 + i + 2] : 0;

    float e0 = l0c + xr0, e1 = l1c + xr1;
    if (HAS_EA) {
      float p0 = 0.f, p1 = 0.f;
      #pragma unroll
      for (int j = 0; j < 6; ++j) { p0 += ecur[j] * w0r[j]; p1 += ecur[j] * w1r[j]; }
      e0 += p0; e1 += p1;
      #pragma unroll
      for (int j = 0; j < 6; ++j) ecur[j] = enxt[j];
    }
    e0 = lrelu(e0); e1 = lrelu(e1);
    float t0 = e0 * a0, t1 = e1 * a1;
    #pragma unroll
    for (int d = 32; d > 0; d >>= 1) { t0 += __shfl_xor(t0, d, 64); t1 += __shfl_xor(t1, d, 64); }
    if (t0 > m0) { float r = __expf(m0 - t0); o0 *= r; d0 *= r; m0 = t0; }
    float p0e = __expf(t0 - m0); d0 += p0e; o0 += p0e * l0c;
    if (t1 > m1) { float r = __expf(m1 - t1); o1 *= r; d1 *= r; m1 = t1; }
    float p1e = __expf(t1 - m1); d1 += p1e; o1 += p1e * l1c;
    sNxt = sNN;
  }
  float r0 = o0 / (d0 + 1e-16f);
  float r1 = o1 / (d1 + 1e-16f);
  out[n * 64 + lane] = 0.5f * (r0 + r1) + bias[lane];
}

// ---------------- BatchNorm (training stats over nodes) ----------------
__global__ __launch_bounds__(256) void k_bn_reduce(const float* __restrict__ h, float* __restrict__ stat) {
  float s = 0.f, s2 = 0.f;
  for (int i = blockIdx.x * 256 + threadIdx.x; i < NN * 64; i += gridDim.x * 256) {
    float v = h[i]; s += v; s2 += v * v;
  }
  __shared__ float sh[512];
  sh[threadIdx.x] = s; sh[256 + threadIdx.x] = s2;
  __syncthreads();
  if (threadIdx.x < 64) {
    int c = threadIdx.x;
    float a = sh[c] + sh[c + 64] + sh[c + 128] + sh[c + 192];
    float b = sh[256 + c] + sh[256 + c + 64] + sh[256 + c + 128] + sh[256 + c + 192];
    atomicAdd(&stat[c], a);
    atomicAdd(&stat[64 + c], b);
  }
}

__global__ void k_bn_final(const float* __restrict__ stat, const float* __restrict__ g,
                           const float* __restrict__ b, float* __restrict__ AB) {
  int c = threadIdx.x;                              // 64 threads
  float mean = stat[c] * (1.f / NN);
  float var  = stat[64 + c] * (1.f / NN) - mean * mean;
  float rstd = rsqrtf(var + 1e-5f);
  float A = g[c] * rstd;
  AB[c] = A; AB[64 + c] = b[c] - mean * A;
}

__global__ __launch_bounds__(256) void k_bn_apply(float* __restrict__ h, const float* __restrict__ AB) {
  int i = blockIdx.x * 256 + threadIdx.x;
  int c = i & 63;
  h[i] = lrelu(h[i] * AB[c] + AB[64 + c]);
}

// ---------------- split h into bf16 hi/lo (per-graph k-major) + per-node sum sq ----------------
// k-major layout: hi[((g*8 + s)*NPG + npg)*8 + e]  (s = k-chunk 0..7, e = elem 0..7)
// -> gram staging is LDS-linear AND global-coalesced simultaneously (kills write conflicts)
__global__ __launch_bounds__(256) void k_split_sq(const float* __restrict__ h,
    unsigned short* __restrict__ hi, unsigned short* __restrict__ lo, float* __restrict__ sq) {
  int wv = threadIdx.x >> 6, lane = threadIdx.x & 63;
  int n = blockIdx.x * 4 + wv;
  int b = n >> 12, npg = n & (NPG - 1);
  float v = h[n * 64 + lane];
  unsigned short hu = f2bf(v);
  float hf = bf2f(hu);
  int idx = ((b * 8 + (lane >> 3)) * NPG + npg) * 8 + (lane & 7);
  hi[idx] = hu;
  lo[idx] = f2bf(v - hf);
  float s = v * v;
  #pragma unroll
  for (int d = 32; d > 0; d >>= 1) s += __shfl_xor(s, d, 64);
  if (lane == 0) sq[n] = s;
}

// ---------------- fused Gram (split-bf16 MFMA, swapped operands) + register top-k ----------------
// 32 rows/block, 4 waves share one B tile: wave = (row-group rg = wv>>1) x (cand-half = wv&1).
// Rank by key = 0.5*sq[c] - dot (monotonic in dist per row); self excluded at merge;
// group-min early-out gates the insertion chain. Exact fp32 refine follows.
__global__ __launch_bounds__(256) void k_gram_topk(
    const unsigned short* __restrict__ hbhi, const unsigned short* __restrict__ hblo,
    const float* __restrict__ sq, int* __restrict__ cand) {
  __shared__ alignas(16) unsigned short Ahi[8 * 32 * 8],  Alo[8 * 32 * 8];   // our 32 rows
  __shared__ alignas(16) unsigned short Bhi[8 * 128 * 8], Blo[8 * 128 * 8];  // 128 candidates
  __shared__ float sqch[128];                                                // 0.5*sq of tile

  int tid = threadIdx.x, wv = tid >> 6, lane = tid & 63;
  int b = blockIdx.x >> 7, rblk = blockIdx.x & 127;
  int gbase = b * NPG, rowbase = gbase + rblk * 32;
  int l15 = lane & 15, l4 = lane >> 4;
  int rg = wv >> 1, chalf = wv & 1;

  // stage A: 256 chunks (8 s x 32 rows), one per thread; LDS-linear + global-coalesced
  {
    int s = tid >> 5, row = tid & 31;
    int gi = ((b * 8 + s) * NPG + rblk * 32 + row) * 8;
    *(uint4*)&Ahi[tid * 8] = *(const uint4*)&hbhi[gi];
    *(uint4*)&Alo[tid * 8] = *(const uint4*)&hblo[gi];
  }
  // prefetch candidate tile 0 into registers (T14)
  uint4 ph[4], pl[4];
  float psq = 0.f;
  #pragma unroll
  for (int r = 0; r < 4; ++r) {
    int chn = tid + r * 256, s = chn >> 7, node = chn & 127;
    int gi = ((b * 8 + s) * NPG + node) * 8;
    ph[r] = *(const uint4*)&hbhi[gi];
    pl[r] = *(const uint4*)&hblo[gi];
  }
  if (tid < 128) psq = 0.5f * sq[gbase + tid];
  __syncthreads();

  int rloc = rg * 16 + l15;
  int rnode = rowbase + rloc;
  // our-row fragments (loop-invariant): B-operand, row = rloc, k-chunk s = ks*4 + l4
  v8s ofh[2], ofl[2];
  #pragma unroll
  for (int ks = 0; ks < 2; ++ks) {
    int s = ks * 4 + l4;
    ofh[ks] = *(v8s*)&Ahi[(s * 32 + rloc) * 8];
    ofl[ks] = *(v8s*)&Alo[(s * 32 + rloc) * 8];
  }

  float td[10]; int ti[10];
  #pragma unroll
  for (int j = 0; j < 10; ++j) { td[j] = 1e30f; ti[j] = 0x7fffffff; }

  for (int it = 0; it < NPG / 128; ++it) {
    // write prefetched tile to LDS (linear: chunk chn -> LDS offset chn*16B)
    #pragma unroll
    for (int r = 0; r < 4; ++r) {
      int chn = tid + r * 256;
      *(uint4*)&Bhi[chn * 8] = ph[r];
      *(uint4*)&Blo[chn * 8] = pl[r];
    }
    if (tid < 128) sqch[tid] = psq;
    // issue prefetch of next tile (overlaps barrier + MFMA + select)
    if (it + 1 < NPG / 128) {
      int cbl = (it + 1) * 128;
      #pragma unroll
      for (int r = 0; r < 4; ++r) {
        int chn = tid + r * 256, s = chn >> 7, node = chn & 127;
        int gi = ((b * 8 + s) * NPG + cbl + node) * 8;
        ph[r] = *(const uint4*)&hbhi[gi];
        pl[r] = *(const uint4*)&hblo[gi];
      }
      if (tid < 128) psq = 0.5f * sq[gbase + cbl + tid];
    }
    __syncthreads();

    int cb = gbase + it * 128;
    #pragma unroll
    for (int cc = 0; cc < 4; ++cc) {
      int cg = chalf * 4 + cc;
      // candidate fragments: A-operand, cand = cg*16 + l15, k-chunk s = ks*4 + l4
      v8s ch0 = *(v8s*)&Bhi[((0 + l4) * 128 + cg * 16 + l15) * 8];
      v8s ch1 = *(v8s*)&Bhi[((4 + l4) * 128 + cg * 16 + l15) * 8];
      v8s cl0 = *(v8s*)&Blo[((0 + l4) * 128 + cg * 16 + l15) * 8];
      v8s cl1 = *(v8s*)&Blo[((4 + l4) * 128 + cg * 16 + l15) * 8];
      // two independent accumulator chains: hi*hi  ||  hi*lo + lo*hi
      v4f accA = {0.f, 0.f, 0.f, 0.f}, accB = {0.f, 0.f, 0.f, 0.f};
      accA = __builtin_amdgcn_mfma_f32_16x16x32_bf16(ch0, ofh[0], accA, 0, 0, 0);
      accB = __builtin_amdgcn_mfma_f32_16x16x32_bf16(ch0, ofl[0], accB, 0, 0, 0);
      accA = __builtin_amdgcn_mfma_f32_16x16x32_bf16(ch1, ofh[1], accA, 0, 0, 0);
      accB = __builtin_amdgcn_mfma_f32_16x16x32_bf16(ch1, ofl[1], accB, 0, 0, 0);
      accB = __builtin_amdgcn_mfma_f32_16x16x32_bf16(cl0, ofh[0], accB, 0, 0, 0);
      accB = __builtin_amdgcn_mfma_f32_16x16x32_bf16(cl1, ofh[1], accB, 0, 0, 0);
      // D layout: cand = l4*4 + r, our = l15 (verified); key = 0.5*sq[c] - dot
      int kb = cg * 16 + l4 * 4;
      float k0 = sqch[kb + 0] - (accA[0] + accB[0]);
      float k1 = sqch[kb + 1] - (accA[1] + accB[1]);
      float k2 = sqch[kb + 2] - (accA[2] + accB[2]);
      float k3 = sqch[kb + 3] - (accA[3] + accB[3]);
      float gmin = fminf(fminf(k0, k1), fminf(k2, k3));
      if (gmin < td[9]) {
        float kk[4] = {k0, k1, k2, k3};
        #pragma unroll
        for (int r = 0; r < 4; ++r) {
          if (kk[r] < td[9]) {
            float cd = kk[r]; int ci = cb + kb + r;
            #pragma unroll
            for (int u = 0; u < 10; ++u) {
              bool bt = cd < td[u];
              float nd = bt ? cd : td[u]; int nc = bt ? ci : ti[u];
              float od = bt ? td[u] : cd; int oc = bt ? ti[u] : ci;
              td[u] = nd; ti[u] = nc; cd = od; ci = oc;
            }
          }
        }
      }
    }
    __syncthreads();   // select done; next iter may overwrite B
  }

  // dump per-lane lists: row rloc has 8 lists (chalf x l4) x 10 entries
  float* mbd = (float*)Bhi;   // 32*8*10*4B = 10240B, fits
  int*   mbi = (int*)Blo;
  int listid = chalf * 4 + l4;
  #pragma unroll
  for (int j = 0; j < 10; ++j) {
    mbd[(rloc * 8 + listid) * 10 + j] = td[j];
    mbi[(rloc * 8 + listid) * 10 + j] = ti[j];
  }
  __syncthreads();
  if (tid < 32) {
    int rn = rowbase + tid;
    float fd[12]; int fi[12];
    #pragma unroll
    for (int j = 0; j < 12; ++j) { fd[j] = 1e30f; fi[j] = 0x7fffffff; }
    #pragma unroll 1
    for (int u = 0; u < 80; ++u) {
      float cd = mbd[tid * 80 + u];
      int   ci = mbi[tid * 80 + u];
      if (ci != rn && (cd < fd[11] || (cd == fd[11] && ci < fi[11]))) {
        #pragma unroll
        for (int v = 0; v < 12; ++v) {
          bool better = (cd < fd[v]) || (cd == fd[v] && ci < fi[v]);
          if (better) { float tf = fd[v]; int tq = fi[v]; fd[v] = cd; fi[v] = ci; cd = tf; ci = tq; }
        }
      }
    }
    #pragma unroll
    for (int j = 0; j < 12; ++j) cand[rn * 12 + j] = fi[j];
  }
}

// ---------------- exact fp32 refinement: top-8 of the 12 candidates ----------------
__global__ __launch_bounds__(256) void k_refine(
    const float* __restrict__ h, const int* __restrict__ cand, int* __restrict__ knn) {
  int wv = threadIdx.x >> 6, lane = threadIdx.x & 63;
  int n = blockIdx.x * 4 + wv;
  float hn = h[n * 64 + lane];
  float td[8]; int ti[8];
  #pragma unroll
  for (int j = 0; j < 8; ++j) { td[j] = 1e30f; ti[j] = 0x7fffffff; }
  #pragma unroll 1
  for (int j = 0; j < 12; ++j) {
    int c = cand[n * 12 + j];
    float df = h[c * 64 + lane] - hn;
    float s = df * df;
    #pragma unroll
    for (int d = 32; d > 0; d >>= 1) s += __shfl_xor(s, d, 64);
    if (s < td[7] || (s == td[7] && c < ti[7])) {
      float cd = s; int ci = c;
      #pragma unroll
      for (int u = 0; u < 8; ++u) {
        bool better = (cd < td[u]) || (cd == td[u] && ci < ti[u]);
        if (better) { float tf = td[u]; int tq = ti[u]; td[u] = cd; ti[u] = ci; cd = tf; ci = tq; }
      }
    }
  }
  #pragma unroll
  for (int u = 0; u < 8; ++u) {
    if (lane == u) knn[n * 8 + u] = ti[u];
  }
}

// ---------------- dynamic-kNN gather + 2-layer MLP + mean over K ----------------
__global__ __launch_bounds__(256) void k_dynmlp(
    const float* __restrict__ h, const int* __restrict__ knn,
    const float* __restrict__ w1, const float* __restrict__ b1,
    const float* __restrict__ w2, const float* __restrict__ b2,
    float* __restrict__ out) {
  __shared__ alignas(16) float smem[128 * 64];      // inT [128][64]; reused as y1T [64][68]
  __shared__ float outacc[8 * 64];
  int t = threadIdx.x;
  int nb = blockIdx.x * 8;
  for (int u = t; u < 512; u += 256) outacc[u] = 0.f;

  // stage msg^T: 64 pairs (8 nodes x 8 k), 128 features
  int p = t & 63;
  int n = nb + (p >> 3);
  int m = knn[n * 8 + (p & 7)];
  for (int qq = (t >> 6); qq < 32; qq += 4) {
    int j0 = qq * 4;
    float4 v;
    if (j0 < 64) {
      v = *(const float4*)(h + n * 64 + j0);
    } else {
      float4 a = *(const float4*)(h + m * 64 + (j0 - 64));
      float4 c = *(const float4*)(h + n * 64 + (j0 - 64));
      v.x = a.x - c.x; v.y = a.y - c.y; v.z = a.z - c.z; v.w = a.w - c.w;
    }
    smem[(j0 + 0) * 64 + p] = v.x;
    smem[(j0 + 1) * 64 + p] = v.y;
    smem[(j0 + 2) * 64 + p] = v.z;
    smem[(j0 + 3) * 64 + p] = v.w;
  }
  __syncthreads();

  int pq = t >> 4, cq = t & 15;
  float acc[4][4];
  #pragma unroll
  for (int c = 0; c < 4; ++c) {
    float bv = b1[cq * 4 + c];
    #pragma unroll
    for (int i = 0; i < 4; ++i) acc[i][c] = bv;
  }
  for (int j = 0; j < 128; ++j) {
    float4 av = *(float4*)&smem[j * 64 + pq * 4];
    float4 wv = *(const float4*)&w1[j * 64 + cq * 4];
    float aa[4] = {av.x, av.y, av.z, av.w};
    float ww[4] = {wv.x, wv.y, wv.z, wv.w};
    #pragma unroll
    for (int i = 0; i < 4; ++i)
      #pragma unroll
      for (int c = 0; c < 4; ++c) acc[i][c] += aa[i] * ww[c];
  }
  __syncthreads();
  #pragma unroll
  for (int c = 0; c < 4; ++c)
    #pragma unroll
    for (int i = 0; i < 4; ++i)
      smem[(cq * 4 + c) * 68 + pq * 4 + i] = lrelu(acc[i][c]);
  __syncthreads();

  float a2[4][4];
  #pragma unroll
  for (int i = 0; i < 4; ++i)
    #pragma unroll
    for (int c = 0; c < 4; ++c) a2[i][c] = 0.f;
  for (int j = 0; j < 64; ++j) {
    float4 av = *(float4*)&smem[j * 68 + pq * 4];
    float4 wv = *(const float4*)&w2[j * 64 + cq * 4];
    float aa[4] = {av.x, av.y, av.z, av.w};
    float ww[4] = {wv.x, wv.y, wv.z, wv.w};
    #pragma unroll
    for (int i = 0; i < 4; ++i)
      #pragma unroll
      for (int c = 0; c < 4; ++c) a2[i][c] += aa[i] * ww[c];
  }
  #pragma unroll
  for (int i = 0; i < 4; ++i) {
    int nloc = (pq * 4 + i) >> 3;
    #pragma unroll
    for (int c = 0; c < 4; ++c) atomicAdd(&outacc[nloc * 64 + cq * 4 + c], a2[i][c]);
  }
  __syncthreads();
  for (int u = t; u < 512; u += 256) {
    out[(nb + (u >> 6)) * 64 + (u & 63)] = outacc[u] * 0.125f + b2[u & 63];
  }
}

// ---------------- GAT2 node transforms (in-dim 64, l+r fused) ----------------
__global__ __launch_bounds__(256) void k_xform64(
    const float* __restrict__ h,
    const float* __restrict__ wl, const float* __restrict__ bl,
    const float* __restrict__ wr, const float* __restrict__ br,
    float* __restrict__ xl, float* __restrict__ xr) {
  __shared__ alignas(16) float hT[64 * 20];         // [j][16 nodes], pad 20
  int t = threadIdx.x;
  int nb = blockIdx.x * 16;
  {
    int n = t >> 4, qj = t & 15;
    float4 v = *(const float4*)(h + (nb + n) * 64 + qj * 4);
    hT[(qj * 4 + 0) * 20 + n] = v.x;
    hT[(qj * 4 + 1) * 20 + n] = v.y;
    hT[(qj * 4 + 2) * 20 + n] = v.z;
    hT[(qj * 4 + 3) * 20 + n] = v.w;
  }
  __syncthreads();
  int pq = t >> 6, cq = t & 63;
  int oc = cq * 4;
  const float* wb; const float* bb; float* ob; int ocl;
  if (oc < 128) { wb = wl + oc;         bb = bl + oc;         ob = xl; ocl = oc; }
  else          { wb = wr + (oc - 128); bb = br + (oc - 128); ob = xr; ocl = oc - 128; }
  float acc[4][4];
  #pragma unroll
  for (int c = 0; c < 4; ++c) {
    float bv = bb[c];
    #pragma unroll
    for (int i = 0; i < 4; ++i) acc[i][c] = bv;
  }
  for (int j = 0; j < 64; ++j) {
    float4 av = *(float4*)&hT[j * 20 + pq * 4];
    float4 wv = *(const float4*)(wb + j * 128);
    float aa[4] = {av.x, av.y, av.z, av.w};
    float ww[4] = {wv.x, wv.y, wv.z, wv.w};
    #pragma unroll
    for (int i = 0; i < 4; ++i)
      #pragma unroll
      for (int c = 0; c < 4; ++c) acc[i][c] += aa[i] * ww[c];
  }
  #pragma unroll
  for (int i = 0; i < 4; ++i) {
    int n = nb + pq * 4 + i;
    #pragma unroll
    for (int c = 0; c < 4; ++c) ob[n * 128 + ocl + c] = acc[i][c];
  }
}

// ---------------- attention-pool gate per node ----------------
__global__ __launch_bounds__(256) void k_gate(
    const float* __restrict__ h3, const float* __restrict__ w1, const float* __restrict__ b1,
    const float* __restrict__ w2, const float* __restrict__ b2, float* __restrict__ gates) {
  __shared__ float hsh[4][64];
  int wv = threadIdx.x >> 6, lane = threadIdx.x & 63;
  int n = blockIdx.x * 4 + wv;
  hsh[wv][lane] = h3[n * 64 + lane];
  __syncthreads();
  float s = b1[lane];
  for (int j = 0; j < 64; ++j) s += hsh[wv][j] * w1[j * 64 + lane];
  float tv = tanhf(s) * w2[lane];
  #pragma unroll
  for (int d = 32; d > 0; d >>= 1) tv += __shfl_xor(tv, d, 64);
  if (lane == 0) gates[n] = tv + b2[0];
}

// ---------------- per-graph softmax pool ----------------
__global__ __launch_bounds__(1024) void k_pool(
    const float* __restrict__ gates, const float* __restrict__ h3,
    float* __restrict__ pexp, float* __restrict__ gpool) {
  int b = blockIdx.x, t = threadIdx.x;
  const float* g = gates + b * NPG;
  __shared__ float red[1024];
  float m = -1e30f;
  for (int i = t; i < NPG; i += 1024) m = fmaxf(m, g[i]);
  red[t] = m; __syncthreads();
  for (int s = 512; s > 0; s >>= 1) { if (t < s) red[t] = fmaxf(red[t], red[t + s]); __syncthreads(); }
  m = red[0]; __syncthreads();
  float sum = 0.f;
  for (int i = t; i < NPG; i += 1024) { float p = __expf(g[i] - m); pexp[b * NPG + i] = p; sum += p; }
  red[t] = sum; __syncthreads();
  for (int s = 512; s > 0; s >>= 1) { if (t < s) red[t] += red[t + s]; __syncthreads(); }
  float den = red[0];
  __syncthreads();
  int grp = t >> 6, c = t & 63;
  float acc = 0.f;
  for (int i = grp; i < NPG; i += 16) acc += pexp[b * NPG + i] * h3[(b * NPG + i) * 64 + c];
  red[t] = acc; __syncthreads();
  if (t < 64) {
    float a = 0.f;
    for (int qq = 0; qq < 16; ++qq) a += red[qq * 64 + t];
    gpool[b * 64 + t] = a / den;
  }
}

// ---------------- context MLP (tiny) ----------------
__global__ void k_ctx(const float* __restrict__ gpool,
                      const float* __restrict__ w1, const float* __restrict__ b1,
                      const float* __restrict__ w2, const float* __restrict__ b2,
                      float* __restrict__ gctx) {
  __shared__ float gsh[64], tsh[64];
  int b = blockIdx.x, c = threadIdx.x;              // 64 threads
  gsh[c] = gpool[b * 64 + c];
  __syncthreads();
  float s = b1[c];
  for (int j = 0; j < 64; ++j) s += gsh[j] * w1[j * 64 + c];
  tsh[c] = lrelu(s);
  __syncthreads();
  float o = b2[c];
  for (int j = 0; j < 64; ++j) o += tsh[j] * w2[j * 64 + c];
  gctx[b * 64 + c] = o;
}

// ---------------- fused decoder: 133->128 -> LN -> 64 -> 3, +x, tanh*CAP ----------------
__global__ __launch_bounds__(128) void k_decoder(
    const float* __restrict__ h3, const float* __restrict__ gctx, const float* __restrict__ x,
    const float* __restrict__ w1, const float* __restrict__ b1,
    const float* __restrict__ lng, const float* __restrict__ lnb,
    const float* __restrict__ w2, const float* __restrict__ b2,
    const float* __restrict__ w3, const float* __restrict__ b3,
    float* __restrict__ out) {
  __shared__ alignas(16) float hf[16 * 136];
  __shared__ alignas(16) float dT[16 * 132];
  __shared__ float d2[16 * 65];
  __shared__ float mu[16], rs[16];
  int t = threadIdx.x;
  int nb = blockIdx.x * 16;
  int gb = nb >> 12;
  for (int u = t; u < 16 * 64; u += 128) { int p = u >> 6, j = u & 63; hf[p * 136 + j] = h3[(nb + p) * 64 + j]; }
  for (int u = t; u < 16 * 64; u += 128) { int p = u >> 6, j = u & 63; hf[p * 136 + 64 + j] = gctx[gb * 64 + j]; }
  for (int u = t; u < 16 * 5; u += 128) { int p = u / 5, j = u % 5; hf[p * 136 + 128 + j] = x[(nb + p) * 5 + j]; }
  __syncthreads();
  float acc[16];
  #pragma unroll
  for (int p = 0; p < 16; ++p) acc[p] = b1[t];
  for (int j4 = 0; j4 < 128; j4 += 4) {
    float w0 = w1[(j4 + 0) * 128 + t], wv1 = w1[(j4 + 1) * 128 + t];
    float wv2 = w1[(j4 + 2) * 128 + t], wv3 = w1[(j4 + 3) * 128 + t];
    #pragma unroll
    for (int p = 0; p < 16; ++p) {
      float4 hv = *(float4*)&hf[p * 136 + j4];
      acc[p] += hv.x * w0 + hv.y * wv1 + hv.z * wv2 + hv.w * wv3;
    }
  }
  for (int j = 128; j < 133; ++j) {
    float w = w1[j * 128 + t];
    #pragma unroll
    for (int p = 0; p < 16; ++p) acc[p] += hf[p * 136 + j] * w;
  }
  #pragma unroll
  for (int p = 0; p < 16; ++p) dT[p * 132 + t] = lrelu(acc[p]);
  __syncthreads();
  if (t < 16) {
    float s = 0.f, s2 = 0.f;
    for (int j = 0; j < 128; ++j) { float v = dT[t * 132 + j]; s += v; s2 += v * v; }
    float mn = s * (1.f / 128.f);
    float vr = s2 * (1.f / 128.f) - mn * mn;
    mu[t] = mn; rs[t] = rsqrtf(vr + 1e-5f);
  }
  __syncthreads();
  float lg = lng[t], lb = lnb[t];
  #pragma unroll
  for (int p = 0; p < 16; ++p) dT[p * 132 + t] = (dT[p * 132 + t] - mu[p]) * rs[p] * lg + lb;
  __syncthreads();
  if (t < 64) {
    float a2[16];
    #pragma unroll
    for (int p = 0; p < 16; ++p) a2[p] = b2[t];
    for (int j4 = 0; j4 < 128; j4 += 4) {
      float w0 = w2[(j4 + 0) * 64 + t], wv1 = w2[(j4 + 1) * 64 + t];
      float wv2 = w2[(j4 + 2) * 64 + t], wv3 = w2[(j4 + 3) * 64 + t];
      #pragma unroll
      for (int p = 0; p < 16; ++p) {
        float4 dv = *(float4*)&dT[p * 132 + j4];
        a2[p] += dv.x * w0 + dv.y * wv1 + dv.z * wv2 + dv.w * wv3;
      }
    }
    #pragma unroll
    for (int p = 0; p < 16; ++p) d2[p * 65 + t] = lrelu(a2[p]);
  }
  __syncthreads();
  if (t < 48) {
    int p = t / 3, k = t % 3;
    float o = b3[k];
    for (int j = 0; j < 64; ++j) o += d2[p * 65 + j] * w3[j * 3 + k];
    out[(nb + p) * 3 + k] = x[(nb + p) * 5 + k] + tanhf(o) * 20.0f;
  }
}

// ---------------- workspace layout (bytes) ----------------
// [0, 16MB): kNN-phase block (hbhi, hblo, sq, knn), later clobbered by xl2 (xform64)
#define O_XL     0ul
#define O_HBHI   0ul
#define O_HBLO   4194304ul
#define O_SQ     8388608ul
#define O_KNN    8519680ul
// [16MB, 32MB): cand during kNN phase, later xr2
#define O_XR     16777216ul
#define O_CAND   16777216ul
#define O_H1     33554432ul    // 8 MB: GAT1 out -> h1 -> (GAT2 out -> h3)
#define O_H2     41943040ul    // 8 MB: dynmlp out -> h2
#define O_CNT    50331648ul
#define O_START  50462720ul
#define O_CUR    50593792ul
#define O_BKT    50724864ul    // edge ids by bucket order (2 MB)
#define O_BSRC   52822016ul    // src node  by bucket order (2 MB)
#define O_STAT   54919168ul
#define O_AB     54919680ul
#define O_GATES  54920192ul
#define O_PEXP   55051264ul
#define O_GPOOL  55182336ul
#define O_GCTX   55184384ul

extern "C" void kernel_launch(void* const* d_in, const int* in_sizes, int n_in,
                              void* d_out, int out_size, void* d_ws, size_t ws_size,
                              hipStream_t stream) {
  (void)in_sizes; (void)n_in; (void)out_size; (void)ws_size;
  const float* x      = (const float*)d_in[0];
  const float* eattr  = (const float*)d_in[1];
  const int*   ei     = (const int*)d_in[2];
  const float* g1_wl  = (const float*)d_in[3];
  const float* g1_bl  = (const float*)d_in[4];
  const float* g1_wr  = (const float*)d_in[5];
  const float* g1_br  = (const float*)d_in[6];
  const float* g1_we  = (const float*)d_in[7];
  const float* g1_att = (const float*)d_in[8];
  const float* g1_bias= (const float*)d_in[9];
  const float* bn1_g  = (const float*)d_in[10];
  const float* bn1_b  = (const float*)d_in[11];
  const float* em_w1  = (const float*)d_in[12];
  const float* em_b1  = (const float*)d_in[13];
  const float* em_w2  = (const float*)d_in[14];
  const float* em_b2  = (const float*)d_in[15];
  const float* bn2_g  = (const float*)d_in[16];
  const float* bn2_b  = (const float*)d_in[17];
  const float* g2_wl  = (const float*)d_in[18];
  const float* g2_bl  = (const float*)d_in[19];
  const float* g2_wr  = (const float*)d_in[20];
  const float* g2_br  = (const float*)d_in[21];
  const float* g2_att = (const float*)d_in[22];
  const float* g2_bias= (const float*)d_in[23];
  const float* bn3_g  = (const float*)d_in[24];
  const float* bn3_b  = (const float*)d_in[25];
  const float* gt_w1  = (const float*)d_in[26];
  const float* gt_b1  = (const float*)d_in[27];
  const float* gt_w2  = (const float*)d_in[28];
  const float* gt_b2  = (const float*)d_in[29];
  const float* cx_w1  = (const float*)d_in[30];
  const float* cx_b1  = (const float*)d_in[31];
  const float* cx_w2  = (const float*)d_in[32];
  const float* cx_b2  = (const float*)d_in[33];
  const float* dc_w1  = (const float*)d_in[34];
  const float* dc_b1  = (const float*)d_in[35];
  const float* ln_g   = (const float*)d_in[36];
  const float* ln_b   = (const float*)d_in[37];
  const float* dc_w2  = (const float*)d_in[38];
  const float* dc_b2  = (const float*)d_in[39];
  const float* dc_w3  = (const float*)d_in[40];
  const float* dc_b3  = (const float*)d_in[41];

  char* ws = (char*)d_ws;
  float* xl    = (float*)(ws + O_XL);
  float* xr    = (float*)(ws + O_XR);
  float* h1    = (float*)(ws + O_H1);
  float* h2    = (float*)(ws + O_H2);
  int*   cnt   = (int*)(ws + O_CNT);
  int*   start = (int*)(ws + O_START);
  int*   cur   = (int*)(ws + O_CUR);
  int*   bkt   = (int*)(ws + O_BKT);
  int*   bsrc  = (int*)(ws + O_BSRC);
  unsigned short* hbhi = (unsigned short*)(ws + O_HBHI);
  unsigned short* hblo = (unsigned short*)(ws + O_HBLO);
  float* sq    = (float*)(ws + O_SQ);
  int*   knn   = (int*)(ws + O_KNN);
  int*   cand  = (int*)(ws + O_CAND);
  float* stat  = (float*)(ws + O_STAT);
  float* AB    = (float*)(ws + O_AB);
  float* gates = (float*)(ws + O_GATES);
  float* pexp  = (float*)(ws + O_PEXP);
  float* gpool = (float*)(ws + O_GPOOL);
  float* gctx  = (float*)(ws + O_GCTX);

  const int* src = ei;
  const int* dst = ei + NE;

  // ---- GAT layer 1 ----
  hipMemsetAsync(cnt, 0, NN * 4, stream);
  k_xform5<<<NN * 128 / 256, 256, 0, stream>>>(x, g1_wl, g1_bl, g1_wr, g1_br, xl, xr);
  k_count<<<NE / 256, 256, 0, stream>>>(dst, cnt);
  k_scan<<<1, 1024, 0, stream>>>(cnt, start, cur);
  k_scatter<<<NE / 256, 256, 0, stream>>>(dst, src, cur, bkt, bsrc);
  k_gat_edge<1><<<NN / 4, 256, 0, stream>>>(xl, xr, eattr, g1_we, g1_att, g1_bias,
                                            start, cnt, bsrc, bkt, h1);
  hipMemsetAsync(stat, 0, 512, stream);
  k_bn_reduce<<<256, 256, 0, stream>>>(h1, stat);
  k_bn_final<<<1, 64, 0, stream>>>(stat, bn1_g, bn1_b, AB);
  k_bn_apply<<<NN * 64 / 256, 256, 0, stream>>>(h1, AB);

  // ---- dynamic kNN (approx MFMA gram + exact fp32 refine) + edge MLP ----
  k_split_sq<<<NN / 4, 256, 0, stream>>>(h1, hbhi, hblo, sq);
  k_gram_topk<<<NGR * (NPG / 32), 256, 0, stream>>>(hbhi, hblo, sq, cand);
  k_refine<<<NN / 4, 256, 0, stream>>>(h1, cand, knn);
  k_dynmlp<<<NN / 8, 256, 0, stream>>>(h1, knn, em_w1, em_b1, em_w2, em_b2, h2);
  hipMemsetAsync(stat, 0, 512, stream);
  k_bn_reduce<<<256, 256, 0, stream>>>(h2, stat);
  k_bn_final<<<1, 64, 0, stream>>>(stat, bn2_g, bn2_b, AB);
  k_bn_apply<<<NN * 64 / 256, 256, 0, stream>>>(h2, AB);

  // ---- GAT layer 2 ----
  k_xform64<<<NN / 16, 256, 0, stream>>>(h2, g2_wl, g2_bl, g2_wr, g2_br, xl, xr);
  k_gat_edge<0><<<NN / 4, 256, 0, stream>>>(xl, xr, nullptr, nullptr, g2_att, g2_bias,
                                            start, cnt, bsrc, bkt, h1);
  hipMemsetAsync(stat, 0, 512, stream);
  k_bn_reduce<<<256, 256, 0, stream>>>(h1, stat);
  k_bn_final<<<1, 64, 0, stream>>>(stat, bn3_g, bn3_b, AB);
  k_bn_apply<<<NN * 64 / 256, 256, 0, stream>>>(h1, AB);   // h1 is now h3

  // ---- pooling + context ----
  k_gate<<<NN / 4, 256, 0, stream>>>(h1, gt_w1, gt_b1, gt_w2, gt_b2, gates);
  k_pool<<<NGR, 1024, 0, stream>>>(gates, h1, pexp, gpool);
  k_ctx<<<NGR, 64, 0, stream>>>(gpool, cx_w1, cx_b1, cx_w2, cx_b2, gctx);

  // ---- decoder ----
  k_decoder<<<NN / 16, 128, 0, stream>>>(h1, gctx, x, dc_w1, dc_b1, ln_g, ln_b,
                                         dc_w2, dc_b2, dc_w3, dc_b3, (float*)d_out);
}

// Round 8
// 1159.828 us; speedup vs baseline: 1.1921x; 1.1921x over previous
//
#include <hip/hip_runtime.h>

#define NN   32768
#define NPG  4096
#define NGR  8
#define NE   524288
#define NEGS 0.2f

typedef float  v4f __attribute__((ext_vector_type(4)));
typedef short  v8s __attribute__((ext_vector_type(8)));

__device__ __forceinline__ float lrelu(float x){ return x > 0.f ? x : NEGS*x; }

// round-to-nearest-even fp32 -> bf16 (bit trick; inputs are finite)
__device__ __forceinline__ unsigned short f2bf(float v){
  unsigned int u = __float_as_uint(v);
  u = u + 0x7fffu + ((u >> 16) & 1u);
  return (unsigned short)(u >> 16);
}
__device__ __forceinline__ float bf2f(unsigned short s){
  return __uint_as_float(((unsigned int)s) << 16);
}

// ---------------- GAT1 node transforms (in-dim 5) ----------------
__global__ __launch_bounds__(256) void k_xform5(
    const float* __restrict__ x,
    const float* __restrict__ wl, const float* __restrict__ bl,
    const float* __restrict__ wr, const float* __restrict__ br,
    float* __restrict__ xl, float* __restrict__ xr) {
  int t = blockIdx.x * 256 + threadIdx.x;          // NN*128 threads
  int n = t >> 7, oc = t & 127;
  const float* xp = x + n * 5;
  float a = bl[oc], b = br[oc];
  #pragma unroll
  for (int j = 0; j < 5; ++j) {
    float v = xp[j];
    a += v * wl[j * 128 + oc];
    b += v * wr[j * 128 + oc];
  }
  xl[t] = a; xr[t] = b;
}

// ---------------- CSR build (bucket edges by dst) ----------------
__global__ __launch_bounds__(256) void k_count(const int* __restrict__ dst, int* __restrict__ cnt) {
  int e = blockIdx.x * 256 + threadIdx.x;
  atomicAdd(&cnt[dst[e]], 1);
}

__global__ __launch_bounds__(1024) void k_scan(const int* __restrict__ cnt,
                                               int* __restrict__ start, int* __restrict__ cur) {
  __shared__ int sh[1024];
  int t = threadIdx.x;
  int base = t * 32;
  int s = 0;
  for (int i = 0; i < 32; ++i) s += cnt[base + i];
  sh[t] = s;
  __syncthreads();
  for (int ofs = 1; ofs < 1024; ofs <<= 1) {
    int v = (t >= ofs) ? sh[t - ofs] : 0;
    __syncthreads();
    sh[t] += v;
    __syncthreads();
  }
  int run = sh[t] - s;                              // exclusive prefix
  for (int i = 0; i < 32; ++i) {
    start[base + i] = run; cur[base + i] = run;
    run += cnt[base + i];
  }
}

__global__ __launch_bounds__(256) void k_scatter(const int* __restrict__ dst,
                                                 const int* __restrict__ srcv,
                                                 int* __restrict__ cur,
                                                 int* __restrict__ bkt_e, int* __restrict__ bkt_s) {
  int e = blockIdx.x * 256 + threadIdx.x;
  int p = atomicAdd(&cur[dst[e]], 1);
  bkt_e[p] = e;
  bkt_s[p] = srcv[e];
}

// ---------------- GATv2 edge pass: one wave per dst node, online softmax,
// software-pipelined gathers (idx prefetch 2-deep, data prefetch 1-deep) ----------------
template<int HAS_EA>
__global__ __launch_bounds__(256) void k_gat_edge(
    const float* __restrict__ xl, const float* __restrict__ xr,
    const float* __restrict__ ea,
    const float* __restrict__ we, const float* __restrict__ att,
    const float* __restrict__ bias,
    const int* __restrict__ start, const int* __restrict__ cnt,
    const int* __restrict__ bsrc, const int* __restrict__ bedge,
    float* __restrict__ out) {
  int wv = threadIdx.x >> 6, lane = threadIdx.x & 63;
  int n = blockIdx.x * 4 + wv;
  int s0 = start[n], deg = cnt[n];
  float xr0 = xr[n * 128 + lane], xr1 = xr[n * 128 + 64 + lane];
  float a0 = att[lane], a1 = att[64 + lane];
  float w0r[6], w1r[6];
  if (HAS_EA) {
    #pragma unroll
    for (int j = 0; j < 6; ++j) { w0r[j] = we[j * 128 + lane]; w1r[j] = we[j * 128 + 64 + lane]; }
  }
  float m0 = -1e30f, m1 = -1e30f, d0 = 0.f, d1 = 0.f, o0 = 0.f, o1 = 0.f;

  float l0 = 0.f, l1 = 0.f, ecur[6], enxt[6];
  int sNxt = 0;
  if (deg > 0) {
    int sCur = bsrc[s0];
    l0 = xl[sCur * 128 + lane]; l1 = xl[sCur * 128 + 64 + lane];
    if (HAS_EA) {
      int e = bedge[s0];
      #pragma unroll
      for (int j = 0; j < 6; ++j) ecur[j] = ea[e * 6 + j];
    }
    if (deg > 1) sNxt = bsrc[s0 + 1];
  }

  for (int i = 0; i < deg; ++i) {
    float l0c = l0, l1c = l1;
    // issue next edge's gathers before computing this edge
    if (i + 1 < deg) {
      l0 = xl[sNxt * 128 + lane]; l1 = xl[sNxt * 128 + 64 + lane];
      if (HAS_EA) {
        int e = bedge[s0 + i + 1];
        #pragma unroll
        for (int j = 0; j < 6; ++j) enxt[j] = ea[e * 6 + j];
      }
    }
    int sNN = (i + 2 < deg) ? bsrc[s0 + i + 2] : 0;

    float e0 = l0c + xr0, e1 = l1c + xr1;
    if (HAS_EA) {
      float p0 = 0.f, p1 = 0.f;
      #pragma unroll
      for (int j = 0; j < 6; ++j) { p0 += ecur[j] * w0r[j]; p1 += ecur[j] * w1r[j]; }
      e0 += p0; e1 += p1;
      #pragma unroll
      for (int j = 0; j < 6; ++j) ecur[j] = enxt[j];
    }
    e0 = lrelu(e0); e1 = lrelu(e1);
    float t0 = e0 * a0, t1 = e1 * a1;
    #pragma unroll
    for (int d = 32; d > 0; d >>= 1) { t0 += __shfl_xor(t0, d, 64); t1 += __shfl_xor(t1, d, 64); }
    if (t0 > m0) { float r = __expf(m0 - t0); o0 *= r; d0 *= r; m0 = t0; }
    float p0e = __expf(t0 - m0); d0 += p0e; o0 += p0e * l0c;
    if (t1 > m1) { float r = __expf(m1 - t1); o1 *= r; d1 *= r; m1 = t1; }
    float p1e = __expf(t1 - m1); d1 += p1e; o1 += p1e * l1c;
    sNxt = sNN;
  }
  float r0 = o0 / (d0 + 1e-16f);
  float r1 = o1 / (d1 + 1e-16f);
  out[n * 64 + lane] = 0.5f * (r0 + r1) + bias[lane];
}

// ---------------- BatchNorm (training stats over nodes) ----------------
__global__ __launch_bounds__(256) void k_bn_reduce(const float* __restrict__ h, float* __restrict__ stat) {
  float s = 0.f, s2 = 0.f;
  for (int i = blockIdx.x * 256 + threadIdx.x; i < NN * 64; i += gridDim.x * 256) {
    float v = h[i]; s += v; s2 += v * v;
  }
  __shared__ float sh[512];
  sh[threadIdx.x] = s; sh[256 + threadIdx.x] = s2;
  __syncthreads();
  if (threadIdx.x < 64) {
    int c = threadIdx.x;
    float a = sh[c] + sh[c + 64] + sh[c + 128] + sh[c + 192];
    float b = sh[256 + c] + sh[256 + c + 64] + sh[256 + c + 128] + sh[256 + c + 192];
    atomicAdd(&stat[c], a);
    atomicAdd(&stat[64 + c], b);
  }
}

__global__ void k_bn_final(const float* __restrict__ stat, const float* __restrict__ g,
                           const float* __restrict__ b, float* __restrict__ AB) {
  int c = threadIdx.x;                              // 64 threads
  float mean = stat[c] * (1.f / NN);
  float var  = stat[64 + c] * (1.f / NN) - mean * mean;
  float rstd = rsqrtf(var + 1e-5f);
  float A = g[c] * rstd;
  AB[c] = A; AB[64 + c] = b[c] - mean * A;
}

__global__ __launch_bounds__(256) void k_bn_apply(float* __restrict__ h, const float* __restrict__ AB) {
  int i = blockIdx.x * 256 + threadIdx.x;
  int c = i & 63;
  h[i] = lrelu(h[i] * AB[c] + AB[64 + c]);
}

// ---------------- split h into bf16 hi/lo (per-graph k-major) + per-node sum sq ----------------
// k-major layout: hi[((g*8 + s)*NPG + npg)*8 + e]  (s = k-chunk 0..7, e = elem 0..7)
// -> gram staging is LDS-linear AND global-coalesced simultaneously
__global__ __launch_bounds__(256) void k_split_sq(const float* __restrict__ h,
    unsigned short* __restrict__ hi, unsigned short* __restrict__ lo, float* __restrict__ sq) {
  int wv = threadIdx.x >> 6, lane = threadIdx.x & 63;
  int n = blockIdx.x * 4 + wv;
  int b = n >> 12, npg = n & (NPG - 1);
  float v = h[n * 64 + lane];
  unsigned short hu = f2bf(v);
  float hf = bf2f(hu);
  int idx = ((b * 8 + (lane >> 3)) * NPG + npg) * 8 + (lane & 7);
  hi[idx] = hu;
  lo[idx] = f2bf(v - hf);
  float s = v * v;
  #pragma unroll
  for (int d = 32; d > 0; d >>= 1) s += __shfl_xor(s, d, 64);
  if (lane == 0) sq[n] = s;
}

// ---------------- fused Gram (split-bf16 MFMA, swapped operands) + register top-k ----------------
// 64 rows/block (512 blocks), XCD swizzle graph = bid&7 (each XCD works one graph -> L2-resident).
// Double-buffered 64-cand LDS tiles; next-tile loads live only between barriers (no spill).
// Rank by key = 0.5*sq[c] - dot (monotonic in dist per row); self excluded at merge.
__global__ __launch_bounds__(256) void k_gram_topk(
    const unsigned short* __restrict__ hbhi, const unsigned short* __restrict__ hblo,
    const float* __restrict__ sq, int* __restrict__ cand) {
  __shared__ alignas(16) unsigned short Ahi[8 * 64 * 8], Alo[8 * 64 * 8];    // our 64 rows, 16 KB
  __shared__ alignas(16) unsigned short Bhi[2 * 8 * 64 * 8];                 // 2 x 64-cand tiles
  __shared__ alignas(16) unsigned short Blo[2 * 8 * 64 * 8];                 // 32 KB total B
  __shared__ float sqch[2][64];

  int tid = threadIdx.x, wv = tid >> 6, lane = tid & 63;
  int b = blockIdx.x & 7, rblk = blockIdx.x >> 3;   // XCD swizzle: graph = bid % 8
  int gbase = b * NPG, rowbase = gbase + rblk * 64;
  int l15 = lane & 15, l4 = lane >> 4;

  // stage A (64 rows): chn = s*64+row, LDS-linear + global-coalesced (k-major global)
  #pragma unroll
  for (int r = 0; r < 2; ++r) {
    int chn = tid + r * 256;
    int s = chn >> 6, row = chn & 63;
    int gi = ((b * 8 + s) * NPG + rblk * 64 + row) * 8;
    *(uint4*)&Ahi[chn * 8] = *(const uint4*)&hbhi[gi];
    *(uint4*)&Alo[chn * 8] = *(const uint4*)&hblo[gi];
  }
  // stage B tile 0 into buffer 0
  #pragma unroll
  for (int r = 0; r < 2; ++r) {
    int chn = tid + r * 256;
    int s = chn >> 6, node = chn & 63;
    int gi = ((b * 8 + s) * NPG + node) * 8;
    *(uint4*)&Bhi[chn * 8] = *(const uint4*)&hbhi[gi];
    *(uint4*)&Blo[chn * 8] = *(const uint4*)&hblo[gi];
  }
  if (tid < 64) sqch[0][tid] = 0.5f * sq[gbase + tid];
  __syncthreads();

  int rloc = wv * 16 + l15;
  int rnode = rowbase + rloc;
  // our-row fragments (loop-invariant): B-operand, row = rloc, k-chunk s = ks*4 + l4
  v8s ofh[2], ofl[2];
  #pragma unroll
  for (int ks = 0; ks < 2; ++ks) {
    int s = ks * 4 + l4;
    ofh[ks] = *(v8s*)&Ahi[(s * 64 + rloc) * 8];
    ofl[ks] = *(v8s*)&Alo[(s * 64 + rloc) * 8];
  }

  float td[10]; int ti[10];
  #pragma unroll
  for (int j = 0; j < 10; ++j) { td[j] = 1e30f; ti[j] = 0x7fffffff; }

  int cur = 0;
  for (int it = 0; it < NPG / 64; ++it) {
    // issue next tile's loads FIRST (overlap with MFMA+select; regs never cross a barrier)
    bool more = (it + 1 < NPG / 64);
    uint4 nh0, nh1, nl0, nl1;
    float nsq = 0.f;
    if (more) {
      int tb = (it + 1) * 64;
      int s0 = tid >> 6, n0 = tid & 63;
      int chn1 = tid + 256, s1 = chn1 >> 6, n1 = chn1 & 63;
      int g0 = ((b * 8 + s0) * NPG + tb + n0) * 8;
      int g1 = ((b * 8 + s1) * NPG + tb + n1) * 8;
      nh0 = *(const uint4*)&hbhi[g0];
      nh1 = *(const uint4*)&hbhi[g1];
      nl0 = *(const uint4*)&hblo[g0];
      nl1 = *(const uint4*)&hblo[g1];
      if (tid < 64) nsq = 0.5f * sq[gbase + tb + tid];
    }

    int base = cur * 512;                 // chunk units: 512 chunks (8 s x 64 nodes) per buffer
    int cb = gbase + it * 64;
    #pragma unroll
    for (int cg = 0; cg < 4; ++cg) {
      // candidate fragments: A-operand, cand = cg*16 + l15, k-chunk s = ks*4 + l4
      v8s ch0 = *(v8s*)&Bhi[(base + (0 + l4) * 64 + cg * 16 + l15) * 8];
      v8s ch1 = *(v8s*)&Bhi[(base + (4 + l4) * 64 + cg * 16 + l15) * 8];
      v8s cl0 = *(v8s*)&Blo[(base + (0 + l4) * 64 + cg * 16 + l15) * 8];
      v8s cl1 = *(v8s*)&Blo[(base + (4 + l4) * 64 + cg * 16 + l15) * 8];
      // two independent accumulator chains: hi*hi  ||  hi*lo + lo*hi
      v4f accA = {0.f, 0.f, 0.f, 0.f}, accB = {0.f, 0.f, 0.f, 0.f};
      accA = __builtin_amdgcn_mfma_f32_16x16x32_bf16(ch0, ofh[0], accA, 0, 0, 0);
      accB = __builtin_amdgcn_mfma_f32_16x16x32_bf16(ch0, ofl[0], accB, 0, 0, 0);
      accA = __builtin_amdgcn_mfma_f32_16x16x32_bf16(ch1, ofh[1], accA, 0, 0, 0);
      accB = __builtin_amdgcn_mfma_f32_16x16x32_bf16(ch1, ofl[1], accB, 0, 0, 0);
      accB = __builtin_amdgcn_mfma_f32_16x16x32_bf16(cl0, ofh[0], accB, 0, 0, 0);
      accB = __builtin_amdgcn_mfma_f32_16x16x32_bf16(cl1, ofh[1], accB, 0, 0, 0);
      // D layout: cand = l4*4 + r, our = l15 (verified); key = 0.5*sq[c] - dot
      int kb = cg * 16 + l4 * 4;
      float k0 = sqch[cur][kb + 0] - (accA[0] + accB[0]);
      float k1 = sqch[cur][kb + 1] - (accA[1] + accB[1]);
      float k2 = sqch[cur][kb + 2] - (accA[2] + accB[2]);
      float k3 = sqch[cur][kb + 3] - (accA[3] + accB[3]);
      float gmin = fminf(fminf(k0, k1), fminf(k2, k3));
      if (gmin < td[9]) {
        float kk[4] = {k0, k1, k2, k3};
        #pragma unroll
        for (int r = 0; r < 4; ++r) {
          if (kk[r] < td[9]) {
            float cd = kk[r]; int ci = cb + kb + r;
            #pragma unroll
            for (int u = 0; u < 10; ++u) {
              bool bt = cd < td[u];
              float nd = bt ? cd : td[u]; int nc = bt ? ci : ti[u];
              float od = bt ? td[u] : cd; int oc = bt ? ti[u] : ci;
              td[u] = nd; ti[u] = nc; cd = od; ci = oc;
            }
          }
        }
      }
    }

    // write prefetched tile into the other buffer, then one barrier
    if (more) {
      int nb_ = (cur ^ 1) * 4096;         // short units: 4096 shorts per buffer
      *(uint4*)&Bhi[nb_ + tid * 8]         = nh0;
      *(uint4*)&Bhi[nb_ + (tid + 256) * 8] = nh1;
      *(uint4*)&Blo[nb_ + tid * 8]         = nl0;
      *(uint4*)&Blo[nb_ + (tid + 256) * 8] = nl1;
      if (tid < 64) sqch[cur ^ 1][tid] = nsq;
    }
    __syncthreads();
    cur ^= 1;
  }

  // dump per-lane lists: row rloc has 4 lists (l4) x 10 entries -> merge scratch in B LDS
  float* mbd = (float*)Bhi;   // 64*4*10*4B = 10240 B, fits in 16 KB
  int*   mbi = (int*)Blo;
  #pragma unroll
  for (int j = 0; j < 10; ++j) {
    mbd[(rloc * 4 + l4) * 10 + j] = td[j];
    mbi[(rloc * 4 + l4) * 10 + j] = ti[j];
  }
  __syncthreads();
  if (tid < 64) {
    int rn = rowbase + tid;
    float fd[12]; int fi[12];
    #pragma unroll
    for (int j = 0; j < 12; ++j) { fd[j] = 1e30f; fi[j] = 0x7fffffff; }
    #pragma unroll 1
    for (int u = 0; u < 40; ++u) {
      float cd = mbd[tid * 40 + u];
      int   ci = mbi[tid * 40 + u];
      if (ci != rn && (cd < fd[11] || (cd == fd[11] && ci < fi[11]))) {
        #pragma unroll
        for (int v = 0; v < 12; ++v) {
          bool better = (cd < fd[v]) || (cd == fd[v] && ci < fi[v]);
          if (better) { float tf = fd[v]; int tq = fi[v]; fd[v] = cd; fi[v] = ci; cd = tf; ci = tq; }
        }
      }
    }
    #pragma unroll
    for (int j = 0; j < 12; ++j) cand[rn * 12 + j] = fi[j];
  }
}

// ---------------- exact fp32 refinement: top-8 of the 12 candidates ----------------
__global__ __launch_bounds__(256) void k_refine(
    const float* __restrict__ h, const int* __restrict__ cand, int* __restrict__ knn) {
  int wv = threadIdx.x >> 6, lane = threadIdx.x & 63;
  int n = blockIdx.x * 4 + wv;
  float hn = h[n * 64 + lane];
  float td[8]; int ti[8];
  #pragma unroll
  for (int j = 0; j < 8; ++j) { td[j] = 1e30f; ti[j] = 0x7fffffff; }
  #pragma unroll 1
  for (int j = 0; j < 12; ++j) {
    int c = cand[n * 12 + j];
    float df = h[c * 64 + lane] - hn;
    float s = df * df;
    #pragma unroll
    for (int d = 32; d > 0; d >>= 1) s += __shfl_xor(s, d, 64);
    if (s < td[7] || (s == td[7] && c < ti[7])) {
      float cd = s; int ci = c;
      #pragma unroll
      for (int u = 0; u < 8; ++u) {
        bool better = (cd < td[u]) || (cd == td[u] && ci < ti[u]);
        if (better) { float tf = td[u]; int tq = ti[u]; td[u] = cd; ti[u] = ci; cd = tf; ci = tq; }
      }
    }
  }
  #pragma unroll
  for (int u = 0; u < 8; ++u) {
    if (lane == u) knn[n * 8 + u] = ti[u];
  }
}

// ---------------- dynamic-kNN gather + 2-layer MLP + mean over K ----------------
__global__ __launch_bounds__(256) void k_dynmlp(
    const float* __restrict__ h, const int* __restrict__ knn,
    const float* __restrict__ w1, const float* __restrict__ b1,
    const float* __restrict__ w2, const float* __restrict__ b2,
    float* __restrict__ out) {
  __shared__ alignas(16) float smem[128 * 64];      // inT [128][64]; reused as y1T [64][68]
  __shared__ float outacc[8 * 64];
  int t = threadIdx.x;
  int nb = blockIdx.x * 8;
  for (int u = t; u < 512; u += 256) outacc[u] = 0.f;

  // stage msg^T: 64 pairs (8 nodes x 8 k), 128 features
  int p = t & 63;
  int n = nb + (p >> 3);
  int m = knn[n * 8 + (p & 7)];
  for (int qq = (t >> 6); qq < 32; qq += 4) {
    int j0 = qq * 4;
    float4 v;
    if (j0 < 64) {
      v = *(const float4*)(h + n * 64 + j0);
    } else {
      float4 a = *(const float4*)(h + m * 64 + (j0 - 64));
      float4 c = *(const float4*)(h + n * 64 + (j0 - 64));
      v.x = a.x - c.x; v.y = a.y - c.y; v.z = a.z - c.z; v.w = a.w - c.w;
    }
    smem[(j0 + 0) * 64 + p] = v.x;
    smem[(j0 + 1) * 64 + p] = v.y;
    smem[(j0 + 2) * 64 + p] = v.z;
    smem[(j0 + 3) * 64 + p] = v.w;
  }
  __syncthreads();

  int pq = t >> 4, cq = t & 15;
  float acc[4][4];
  #pragma unroll
  for (int c = 0; c < 4; ++c) {
    float bv = b1[cq * 4 + c];
    #pragma unroll
    for (int i = 0; i < 4; ++i) acc[i][c] = bv;
  }
  for (int j = 0; j < 128; ++j) {
    float4 av = *(float4*)&smem[j * 64 + pq * 4];
    float4 wv = *(const float4*)&w1[j * 64 + cq * 4];
    float aa[4] = {av.x, av.y, av.z, av.w};
    float ww[4] = {wv.x, wv.y, wv.z, wv.w};
    #pragma unroll
    for (int i = 0; i < 4; ++i)
      #pragma unroll
      for (int c = 0; c < 4; ++c) acc[i][c] += aa[i] * ww[c];
  }
  __syncthreads();
  #pragma unroll
  for (int c = 0; c < 4; ++c)
    #pragma unroll
    for (int i = 0; i < 4; ++i)
      smem[(cq * 4 + c) * 68 + pq * 4 + i] = lrelu(acc[i][c]);
  __syncthreads();

  float a2[4][4];
  #pragma unroll
  for (int i = 0; i < 4; ++i)
    #pragma unroll
    for (int c = 0; c < 4; ++c) a2[i][c] = 0.f;
  for (int j = 0; j < 64; ++j) {
    float4 av = *(float4*)&smem[j * 68 + pq * 4];
    float4 wv = *(const float4*)&w2[j * 64 + cq * 4];
    float aa[4] = {av.x, av.y, av.z, av.w};
    float ww[4] = {wv.x, wv.y, wv.z, wv.w};
    #pragma unroll
    for (int i = 0; i < 4; ++i)
      #pragma unroll
      for (int c = 0; c < 4; ++c) a2[i][c] += aa[i] * ww[c];
  }
  #pragma unroll
  for (int i = 0; i < 4; ++i) {
    int nloc = (pq * 4 + i) >> 3;
    #pragma unroll
    for (int c = 0; c < 4; ++c) atomicAdd(&outacc[nloc * 64 + cq * 4 + c], a2[i][c]);
  }
  __syncthreads();
  for (int u = t; u < 512; u += 256) {
    out[(nb + (u >> 6)) * 64 + (u & 63)] = outacc[u] * 0.125f + b2[u & 63];
  }
}

// ---------------- GAT2 node transforms (in-dim 64, l+r fused) ----------------
__global__ __launch_bounds__(256) void k_xform64(
    const float* __restrict__ h,
    const float* __restrict__ wl, const float* __restrict__ bl,
    const float* __restrict__ wr, const float* __restrict__ br,
    float* __restrict__ xl, float* __restrict__ xr) {
  __shared__ alignas(16) float hT[64 * 20];         // [j][16 nodes], pad 20
  int t = threadIdx.x;
  int nb = blockIdx.x * 16;
  {
    int n = t >> 4, qj = t & 15;
    float4 v = *(const float4*)(h + (nb + n) * 64 + qj * 4);
    hT[(qj * 4 + 0) * 20 + n] = v.x;
    hT[(qj * 4 + 1) * 20 + n] = v.y;
    hT[(qj * 4 + 2) * 20 + n] = v.z;
    hT[(qj * 4 + 3) * 20 + n] = v.w;
  }
  __syncthreads();
  int pq = t >> 6, cq = t & 63;
  int oc = cq * 4;
  const float* wb; const float* bb; float* ob; int ocl;
  if (oc < 128) { wb = wl + oc;         bb = bl + oc;         ob = xl; ocl = oc; }
  else          { wb = wr + (oc - 128); bb = br + (oc - 128); ob = xr; ocl = oc - 128; }
  float acc[4][4];
  #pragma unroll
  for (int c = 0; c < 4; ++c) {
    float bv = bb[c];
    #pragma unroll
    for (int i = 0; i < 4; ++i) acc[i][c] = bv;
  }
  for (int j = 0; j < 64; ++j) {
    float4 av = *(float4*)&hT[j * 20 + pq * 4];
    float4 wv = *(const float4*)(wb + j * 128);
    float aa[4] = {av.x, av.y, av.z, av.w};
    float ww[4] = {wv.x, wv.y, wv.z, wv.w};
    #pragma unroll
    for (int i = 0; i < 4; ++i)
      #pragma unroll
      for (int c = 0; c < 4; ++c) acc[i][c] += aa[i] * ww[c];
  }
  #pragma unroll
  for (int i = 0; i < 4; ++i) {
    int n = nb + pq * 4 + i;
    #pragma unroll
    for (int c = 0; c < 4; ++c) ob[n * 128 + ocl + c] = acc[i][c];
  }
}

// ---------------- attention-pool gate per node ----------------
__global__ __launch_bounds__(256) void k_gate(
    const float* __restrict__ h3, const float* __restrict__ w1, const float* __restrict__ b1,
    const float* __restrict__ w2, const float* __restrict__ b2, float* __restrict__ gates) {
  __shared__ float hsh[4][64];
  int wv = threadIdx.x >> 6, lane = threadIdx.x & 63;
  int n = blockIdx.x * 4 + wv;
  hsh[wv][lane] = h3[n * 64 + lane];
  __syncthreads();
  float s = b1[lane];
  for (int j = 0; j < 64; ++j) s += hsh[wv][j] * w1[j * 64 + lane];
  float tv = tanhf(s) * w2[lane];
  #pragma unroll
  for (int d = 32; d > 0; d >>= 1) tv += __shfl_xor(tv, d, 64);
  if (lane == 0) gates[n] = tv + b2[0];
}

// ---------------- per-graph softmax pool ----------------
__global__ __launch_bounds__(1024) void k_pool(
    const float* __restrict__ gates, const float* __restrict__ h3,
    float* __restrict__ pexp, float* __restrict__ gpool) {
  int b = blockIdx.x, t = threadIdx.x;
  const float* g = gates + b * NPG;
  __shared__ float red[1024];
  float m = -1e30f;
  for (int i = t; i < NPG; i += 1024) m = fmaxf(m, g[i]);
  red[t] = m; __syncthreads();
  for (int s = 512; s > 0; s >>= 1) { if (t < s) red[t] = fmaxf(red[t], red[t + s]); __syncthreads(); }
  m = red[0]; __syncthreads();
  float sum = 0.f;
  for (int i = t; i < NPG; i += 1024) { float p = __expf(g[i] - m); pexp[b * NPG + i] = p; sum += p; }
  red[t] = sum; __syncthreads();
  for (int s = 512; s > 0; s >>= 1) { if (t < s) red[t] += red[t + s]; __syncthreads(); }
  float den = red[0];
  __syncthreads();
  int grp = t >> 6, c = t & 63;
  float acc = 0.f;
  for (int i = grp; i < NPG; i += 16) acc += pexp[b * NPG + i] * h3[(b * NPG + i) * 64 + c];
  red[t] = acc; __syncthreads();
  if (t < 64) {
    float a = 0.f;
    for (int qq = 0; qq < 16; ++qq) a += red[qq * 64 + t];
    gpool[b * 64 + t] = a / den;
  }
}

// ---------------- context MLP (tiny) ----------------
__global__ void k_ctx(const float* __restrict__ gpool,
                      const float* __restrict__ w1, const float* __restrict__ b1,
                      const float* __restrict__ w2, const float* __restrict__ b2,
                      float* __restrict__ gctx) {
  __shared__ float gsh[64], tsh[64];
  int b = blockIdx.x, c = threadIdx.x;              // 64 threads
  gsh[c] = gpool[b * 64 + c];
  __syncthreads();
  float s = b1[c];
  for (int j = 0; j < 64; ++j) s += gsh[j] * w1[j * 64 + c];
  tsh[c] = lrelu(s);
  __syncthreads();
  float o = b2[c];
  for (int j = 0; j < 64; ++j) o += tsh[j] * w2[j * 64 + c];
  gctx[b * 64 + c] = o;
}

// ---------------- fused decoder: 133->128 -> LN -> 64 -> 3, +x, tanh*CAP ----------------
__global__ __launch_bounds__(128) void k_decoder(
    const float* __restrict__ h3, const float* __restrict__ gctx, const float* __restrict__ x,
    const float* __restrict__ w1, const float* __restrict__ b1,
    const float* __restrict__ lng, const float* __restrict__ lnb,
    const float* __restrict__ w2, const float* __restrict__ b2,
    const float* __restrict__ w3, const float* __restrict__ b3,
    float* __restrict__ out) {
  __shared__ alignas(16) float hf[16 * 136];
  __shared__ alignas(16) float dT[16 * 132];
  __shared__ float d2[16 * 65];
  __shared__ float mu[16], rs[16];
  int t = threadIdx.x;
  int nb = blockIdx.x * 16;
  int gb = nb >> 12;
  for (int u = t; u < 16 * 64; u += 128) { int p = u >> 6, j = u & 63; hf[p * 136 + j] = h3[(nb + p) * 64 + j]; }
  for (int u = t; u < 16 * 64; u += 128) { int p = u >> 6, j = u & 63; hf[p * 136 + 64 + j] = gctx[gb * 64 + j]; }
  for (int u = t; u < 16 * 5; u += 128) { int p = u / 5, j = u % 5; hf[p * 136 + 128 + j] = x[(nb + p) * 5 + j]; }
  __syncthreads();
  float acc[16];
  #pragma unroll
  for (int p = 0; p < 16; ++p) acc[p] = b1[t];
  for (int j4 = 0; j4 < 128; j4 += 4) {
    float w0 = w1[(j4 + 0) * 128 + t], wv1 = w1[(j4 + 1) * 128 + t];
    float wv2 = w1[(j4 + 2) * 128 + t], wv3 = w1[(j4 + 3) * 128 + t];
    #pragma unroll
    for (int p = 0; p < 16; ++p) {
      float4 hv = *(float4*)&hf[p * 136 + j4];
      acc[p] += hv.x * w0 + hv.y * wv1 + hv.z * wv2 + hv.w * wv3;
    }
  }
  for (int j = 128; j < 133; ++j) {
    float w = w1[j * 128 + t];
    #pragma unroll
    for (int p = 0; p < 16; ++p) acc[p] += hf[p * 136 + j] * w;
  }
  #pragma unroll
  for (int p = 0; p < 16; ++p) dT[p * 132 + t] = lrelu(acc[p]);
  __syncthreads();
  if (t < 16) {
    float s = 0.f, s2 = 0.f;
    for (int j = 0; j < 128; ++j) { float v = dT[t * 132 + j]; s += v; s2 += v * v; }
    float mn = s * (1.f / 128.f);
    float vr = s2 * (1.f / 128.f) - mn * mn;
    mu[t] = mn; rs[t] = rsqrtf(vr + 1e-5f);
  }
  __syncthreads();
  float lg = lng[t], lb = lnb[t];
  #pragma unroll
  for (int p = 0; p < 16; ++p) dT[p * 132 + t] = (dT[p * 132 + t] - mu[p]) * rs[p] * lg + lb;
  __syncthreads();
  if (t < 64) {
    float a2[16];
    #pragma unroll
    for (int p = 0; p < 16; ++p) a2[p] = b2[t];
    for (int j4 = 0; j4 < 128; j4 += 4) {
      float w0 = w2[(j4 + 0) * 64 + t], wv1 = w2[(j4 + 1) * 64 + t];
      float wv2 = w2[(j4 + 2) * 64 + t], wv3 = w2[(j4 + 3) * 64 + t];
      #pragma unroll
      for (int p = 0; p < 16; ++p) {
        float4 dv = *(float4*)&dT[p * 132 + j4];
        a2[p] += dv.x * w0 + dv.y * wv1 + dv.z * wv2 + dv.w * wv3;
      }
    }
    #pragma unroll
    for (int p = 0; p < 16; ++p) d2[p * 65 + t] = lrelu(a2[p]);
  }
  __syncthreads();
  if (t < 48) {
    int p = t / 3, k = t % 3;
    float o = b3[k];
    for (int j = 0; j < 64; ++j) o += d2[p * 65 + j] * w3[j * 3 + k];
    out[(nb + p) * 3 + k] = x[(nb + p) * 5 + k] + tanhf(o) * 20.0f;
  }
}

// ---------------- workspace layout (bytes) ----------------
// [0, 16MB): kNN-phase block (hbhi, hblo, sq, knn), later clobbered by xl2 (xform64)
#define O_XL     0ul
#define O_HBHI   0ul
#define O_HBLO   4194304ul
#define O_SQ     8388608ul
#define O_KNN    8519680ul
// [16MB, 32MB): cand during kNN phase, later xr2
#define O_XR     16777216ul
#define O_CAND   16777216ul
#define O_H1     33554432ul    // 8 MB: GAT1 out -> h1 -> (GAT2 out -> h3)
#define O_H2     41943040ul    // 8 MB: dynmlp out -> h2
#define O_CNT    50331648ul
#define O_START  50462720ul
#define O_CUR    50593792ul
#define O_BKT    50724864ul    // edge ids by bucket order (2 MB)
#define O_BSRC   52822016ul    // src node  by bucket order (2 MB)
#define O_STAT   54919168ul
#define O_AB     54919680ul
#define O_GATES  54920192ul
#define O_PEXP   55051264ul
#define O_GPOOL  55182336ul
#define O_GCTX   55184384ul

extern "C" void kernel_launch(void* const* d_in, const int* in_sizes, int n_in,
                              void* d_out, int out_size, void* d_ws, size_t ws_size,
                              hipStream_t stream) {
  (void)in_sizes; (void)n_in; (void)out_size; (void)ws_size;
  const float* x      = (const float*)d_in[0];
  const float* eattr  = (const float*)d_in[1];
  const int*   ei     = (const int*)d_in[2];
  const float* g1_wl  = (const float*)d_in[3];
  const float* g1_bl  = (const float*)d_in[4];
  const float* g1_wr  = (const float*)d_in[5];
  const float* g1_br  = (const float*)d_in[6];
  const float* g1_we  = (const float*)d_in[7];
  const float* g1_att = (const float*)d_in[8];
  const float* g1_bias= (const float*)d_in[9];
  const float* bn1_g  = (const float*)d_in[10];
  const float* bn1_b  = (const float*)d_in[11];
  const float* em_w1  = (const float*)d_in[12];
  const float* em_b1  = (const float*)d_in[13];
  const float* em_w2  = (const float*)d_in[14];
  const float* em_b2  = (const float*)d_in[15];
  const float* bn2_g  = (const float*)d_in[16];
  const float* bn2_b  = (const float*)d_in[17];
  const float* g2_wl  = (const float*)d_in[18];
  const float* g2_bl  = (const float*)d_in[19];
  const float* g2_wr  = (const float*)d_in[20];
  const float* g2_br  = (const float*)d_in[21];
  const float* g2_att = (const float*)d_in[22];
  const float* g2_bias= (const float*)d_in[23];
  const float* bn3_g  = (const float*)d_in[24];
  const float* bn3_b  = (const float*)d_in[25];
  const float* gt_w1  = (const float*)d_in[26];
  const float* gt_b1  = (const float*)d_in[27];
  const float* gt_w2  = (const float*)d_in[28];
  const float* gt_b2  = (const float*)d_in[29];
  const float* cx_w1  = (const float*)d_in[30];
  const float* cx_b1  = (const float*)d_in[31];
  const float* cx_w2  = (const float*)d_in[32];
  const float* cx_b2  = (const float*)d_in[33];
  const float* dc_w1  = (const float*)d_in[34];
  const float* dc_b1  = (const float*)d_in[35];
  const float* ln_g   = (const float*)d_in[36];
  const float* ln_b   = (const float*)d_in[37];
  const float* dc_w2  = (const float*)d_in[38];
  const float* dc_b2  = (const float*)d_in[39];
  const float* dc_w3  = (const float*)d_in[40];
  const float* dc_b3  = (const float*)d_in[41];

  char* ws = (char*)d_ws;
  float* xl    = (float*)(ws + O_XL);
  float* xr    = (float*)(ws + O_XR);
  float* h1    = (float*)(ws + O_H1);
  float* h2    = (float*)(ws + O_H2);
  int*   cnt   = (int*)(ws + O_CNT);
  int*   start = (int*)(ws + O_START);
  int*   cur   = (int*)(ws + O_CUR);
  int*   bkt   = (int*)(ws + O_BKT);
  int*   bsrc  = (int*)(ws + O_BSRC);
  unsigned short* hbhi = (unsigned short*)(ws + O_HBHI);
  unsigned short* hblo = (unsigned short*)(ws + O_HBLO);
  float* sq    = (float*)(ws + O_SQ);
  int*   knn   = (int*)(ws + O_KNN);
  int*   cand  = (int*)(ws + O_CAND);
  float* stat  = (float*)(ws + O_STAT);
  float* AB    = (float*)(ws + O_AB);
  float* gates = (float*)(ws + O_GATES);
  float* pexp  = (float*)(ws + O_PEXP);
  float* gpool = (float*)(ws + O_GPOOL);
  float* gctx  = (float*)(ws + O_GCTX);

  const int* src = ei;
  const int* dst = ei + NE;

  // ---- GAT layer 1 ----
  hipMemsetAsync(cnt, 0, NN * 4, stream);
  k_xform5<<<NN * 128 / 256, 256, 0, stream>>>(x, g1_wl, g1_bl, g1_wr, g1_br, xl, xr);
  k_count<<<NE / 256, 256, 0, stream>>>(dst, cnt);
  k_scan<<<1, 1024, 0, stream>>>(cnt, start, cur);
  k_scatter<<<NE / 256, 256, 0, stream>>>(dst, src, cur, bkt, bsrc);
  k_gat_edge<1><<<NN / 4, 256, 0, stream>>>(xl, xr, eattr, g1_we, g1_att, g1_bias,
                                            start, cnt, bsrc, bkt, h1);
  hipMemsetAsync(stat, 0, 512, stream);
  k_bn_reduce<<<256, 256, 0, stream>>>(h1, stat);
  k_bn_final<<<1, 64, 0, stream>>>(stat, bn1_g, bn1_b, AB);
  k_bn_apply<<<NN * 64 / 256, 256, 0, stream>>>(h1, AB);

  // ---- dynamic kNN (approx MFMA gram + exact fp32 refine) + edge MLP ----
  k_split_sq<<<NN / 4, 256, 0, stream>>>(h1, hbhi, hblo, sq);
  k_gram_topk<<<NGR * (NPG / 64), 256, 0, stream>>>(hbhi, hblo, sq, cand);
  k_refine<<<NN / 4, 256, 0, stream>>>(h1, cand, knn);
  k_dynmlp<<<NN / 8, 256, 0, stream>>>(h1, knn, em_w1, em_b1, em_w2, em_b2, h2);
  hipMemsetAsync(stat, 0, 512, stream);
  k_bn_reduce<<<256, 256, 0, stream>>>(h2, stat);
  k_bn_final<<<1, 64, 0, stream>>>(stat, bn2_g, bn2_b, AB);
  k_bn_apply<<<NN * 64 / 256, 256, 0, stream>>>(h2, AB);

  // ---- GAT layer 2 ----
  k_xform64<<<NN / 16, 256, 0, stream>>>(h2, g2_wl, g2_bl, g2_wr, g2_br, xl, xr);
  k_gat_edge<0><<<NN / 4, 256, 0, stream>>>(xl, xr, nullptr, nullptr, g2_att, g2_bias,
                                            start, cnt, bsrc, bkt, h1);
  hipMemsetAsync(stat, 0, 512, stream);
  k_bn_reduce<<<256, 256, 0, stream>>>(h1, stat);
  k_bn_final<<<1, 64, 0, stream>>>(stat, bn3_g, bn3_b, AB);
  k_bn_apply<<<NN * 64 / 256, 256, 0, stream>>>(h1, AB);   // h1 is now h3

  // ---- pooling + context ----
  k_gate<<<NN / 4, 256, 0, stream>>>(h1, gt_w1, gt_b1, gt_w2, gt_b2, gates);
  k_pool<<<NGR, 1024, 0, stream>>>(gates, h1, pexp, gpool);
  k_ctx<<<NGR, 64, 0, stream>>>(gpool, cx_w1, cx_b1, cx_w2, cx_b2, gctx);

  // ---- decoder ----
  k_decoder<<<NN / 16, 128, 0, stream>>>(h1, gctx, x, dc_w1, dc_b1, ln_g, ln_b,
                                         dc_w2, dc_b2, dc_w3, dc_b3, (float*)d_out);
}

// Round 9
// 1028.036 us; speedup vs baseline: 1.3449x; 1.1282x over previous
//
#include <hip/hip_runtime.h>

#define NN   32768
#define NPG  4096
#define NGR  8
#define NE   524288
#define NEGS 0.2f

typedef float  v4f __attribute__((ext_vector_type(4)));
typedef short  v8s __attribute__((ext_vector_type(8)));

__device__ __forceinline__ float lrelu(float x){ return x > 0.f ? x : NEGS*x; }

// round-to-nearest-even fp32 -> bf16 (bit trick; inputs are finite)
__device__ __forceinline__ unsigned short f2bf(float v){
  unsigned int u = __float_as_uint(v);
  u = u + 0x7fffu + ((u >> 16) & 1u);
  return (unsigned short)(u >> 16);
}
__device__ __forceinline__ float bf2f(unsigned short s){
  return __uint_as_float(((unsigned int)s) << 16);
}

// ---------------- GAT1 node transforms (in-dim 5) ----------------
__global__ __launch_bounds__(256) void k_xform5(
    const float* __restrict__ x,
    const float* __restrict__ wl, const float* __restrict__ bl,
    const float* __restrict__ wr, const float* __restrict__ br,
    float* __restrict__ xl, float* __restrict__ xr) {
  int t = blockIdx.x * 256 + threadIdx.x;          // NN*128 threads
  int n = t >> 7, oc = t & 127;
  const float* xp = x + n * 5;
  float a = bl[oc], b = br[oc];
  #pragma unroll
  for (int j = 0; j < 5; ++j) {
    float v = xp[j];
    a += v * wl[j * 128 + oc];
    b += v * wr[j * 128 + oc];
  }
  xl[t] = a; xr[t] = b;
}

// ---------------- CSR build (bucket edges by dst) ----------------
__global__ __launch_bounds__(256) void k_count(const int* __restrict__ dst, int* __restrict__ cnt) {
  int e = blockIdx.x * 256 + threadIdx.x;
  atomicAdd(&cnt[dst[e]], 1);
}

__global__ __launch_bounds__(1024) void k_scan(const int* __restrict__ cnt,
                                               int* __restrict__ start, int* __restrict__ cur) {
  __shared__ int sh[1024];
  int t = threadIdx.x;
  int base = t * 32;
  int s = 0;
  for (int i = 0; i < 32; ++i) s += cnt[base + i];
  sh[t] = s;
  __syncthreads();
  for (int ofs = 1; ofs < 1024; ofs <<= 1) {
    int v = (t >= ofs) ? sh[t - ofs] : 0;
    __syncthreads();
    sh[t] += v;
    __syncthreads();
  }
  int run = sh[t] - s;                              // exclusive prefix
  for (int i = 0; i < 32; ++i) {
    start[base + i] = run; cur[base + i] = run;
    run += cnt[base + i];
  }
}

__global__ __launch_bounds__(256) void k_scatter(const int* __restrict__ dst,
                                                 const int* __restrict__ srcv,
                                                 int* __restrict__ cur,
                                                 int* __restrict__ bkt_e, int* __restrict__ bkt_s) {
  int e = blockIdx.x * 256 + threadIdx.x;
  int p = atomicAdd(&cur[dst[e]], 1);
  bkt_e[p] = e;
  bkt_s[p] = srcv[e];
}

// ---------------- GATv2 edge pass: one wave per dst node, online softmax,
// 2-edge pairing (4 interleaved reduce trees, one rescale per pair) + 1-pair prefetch ----
template<int HAS_EA>
__global__ __launch_bounds__(256) void k_gat_edge(
    const float* __restrict__ xl, const float* __restrict__ xr,
    const float* __restrict__ ea,
    const float* __restrict__ we, const float* __restrict__ att,
    const float* __restrict__ bias,
    const int* __restrict__ start, const int* __restrict__ cnt,
    const int* __restrict__ bsrc, const int* __restrict__ bedge,
    float* __restrict__ out) {
  int wv = threadIdx.x >> 6, lane = threadIdx.x & 63;
  int n = blockIdx.x * 4 + wv;
  int s0 = start[n], deg = cnt[n];
  float xr0 = xr[n * 128 + lane], xr1 = xr[n * 128 + 64 + lane];
  float a0 = att[lane], a1 = att[64 + lane];
  float w0r[6], w1r[6];
  if (HAS_EA) {
    #pragma unroll
    for (int j = 0; j < 6; ++j) { w0r[j] = we[j * 128 + lane]; w1r[j] = we[j * 128 + 64 + lane]; }
  }
  float m0 = -1e30f, m1 = -1e30f, d0 = 0.f, d1 = 0.f, o0 = 0.f, o1 = 0.f;

  int np = deg >> 1;
  float A0 = 0.f, A1 = 0.f, B0 = 0.f, B1 = 0.f;
  float NA0 = 0.f, NA1 = 0.f, NB0 = 0.f, NB1 = 0.f;
  float EA[6], EB[6], NEA[6], NEB[6];
  if (np > 0) {
    int sa = bsrc[s0], sb = bsrc[s0 + 1];
    A0 = xl[sa * 128 + lane]; A1 = xl[sa * 128 + 64 + lane];
    B0 = xl[sb * 128 + lane]; B1 = xl[sb * 128 + 64 + lane];
    if (HAS_EA) {
      int eai = bedge[s0], ebi = bedge[s0 + 1];
      #pragma unroll
      for (int j = 0; j < 6; ++j) { EA[j] = ea[eai * 6 + j]; EB[j] = ea[ebi * 6 + j]; }
    }
  }

  for (int p = 0; p < np; ++p) {
    if (p + 1 < np) {
      int i2 = s0 + 2 * (p + 1);
      int sa = bsrc[i2], sb = bsrc[i2 + 1];
      NA0 = xl[sa * 128 + lane]; NA1 = xl[sa * 128 + 64 + lane];
      NB0 = xl[sb * 128 + lane]; NB1 = xl[sb * 128 + 64 + lane];
      if (HAS_EA) {
        int eai = bedge[i2], ebi = bedge[i2 + 1];
        #pragma unroll
        for (int j = 0; j < 6; ++j) { NEA[j] = ea[eai * 6 + j]; NEB[j] = ea[ebi * 6 + j]; }
      }
    }
    float e0a = A0 + xr0, e1a = A1 + xr1, e0b = B0 + xr0, e1b = B1 + xr1;
    if (HAS_EA) {
      float pa0 = 0.f, pa1 = 0.f, pb0 = 0.f, pb1 = 0.f;
      #pragma unroll
      for (int j = 0; j < 6; ++j) {
        pa0 += EA[j] * w0r[j]; pa1 += EA[j] * w1r[j];
        pb0 += EB[j] * w0r[j]; pb1 += EB[j] * w1r[j];
      }
      e0a += pa0; e1a += pa1; e0b += pb0; e1b += pb1;
    }
    e0a = lrelu(e0a); e1a = lrelu(e1a); e0b = lrelu(e0b); e1b = lrelu(e1b);
    float ta0 = e0a * a0, ta1 = e1a * a1, tb0 = e0b * a0, tb1 = e1b * a1;
    #pragma unroll
    for (int d = 32; d > 0; d >>= 1) {
      ta0 += __shfl_xor(ta0, d, 64); ta1 += __shfl_xor(ta1, d, 64);
      tb0 += __shfl_xor(tb0, d, 64); tb1 += __shfl_xor(tb1, d, 64);
    }
    // head 0: paired online-softmax update
    float tm0 = fmaxf(ta0, tb0);
    if (tm0 > m0) { float r = __expf(m0 - tm0); o0 *= r; d0 *= r; m0 = tm0; }
    float pa = __expf(ta0 - m0), pb = __expf(tb0 - m0);
    d0 += pa + pb; o0 += pa * A0 + pb * B0;
    // head 1
    float tm1 = fmaxf(ta1, tb1);
    if (tm1 > m1) { float r = __expf(m1 - tm1); o1 *= r; d1 *= r; m1 = tm1; }
    float qa = __expf(ta1 - m1), qb = __expf(tb1 - m1);
    d1 += qa + qb; o1 += qa * A1 + qb * B1;
    // rotate prefetch buffers
    A0 = NA0; A1 = NA1; B0 = NB0; B1 = NB1;
    if (HAS_EA) {
      #pragma unroll
      for (int j = 0; j < 6; ++j) { EA[j] = NEA[j]; EB[j] = NEB[j]; }
    }
  }

  if (deg & 1) {                                    // tail edge
    int i = s0 + deg - 1;
    int s = bsrc[i];
    float l0 = xl[s * 128 + lane], l1 = xl[s * 128 + 64 + lane];
    float e0 = l0 + xr0, e1 = l1 + xr1;
    if (HAS_EA) {
      int e = bedge[i];
      float p0 = 0.f, p1 = 0.f;
      #pragma unroll
      for (int j = 0; j < 6; ++j) { float v = ea[e * 6 + j]; p0 += v * w0r[j]; p1 += v * w1r[j]; }
      e0 += p0; e1 += p1;
    }
    e0 = lrelu(e0); e1 = lrelu(e1);
    float t0 = e0 * a0, t1 = e1 * a1;
    #pragma unroll
    for (int d = 32; d > 0; d >>= 1) { t0 += __shfl_xor(t0, d, 64); t1 += __shfl_xor(t1, d, 64); }
    if (t0 > m0) { float r = __expf(m0 - t0); o0 *= r; d0 *= r; m0 = t0; }
    float p0e = __expf(t0 - m0); d0 += p0e; o0 += p0e * l0;
    if (t1 > m1) { float r = __expf(m1 - t1); o1 *= r; d1 *= r; m1 = t1; }
    float p1e = __expf(t1 - m1); d1 += p1e; o1 += p1e * l1;
  }

  float r0 = o0 / (d0 + 1e-16f);
  float r1 = o1 / (d1 + 1e-16f);
  out[n * 64 + lane] = 0.5f * (r0 + r1) + bias[lane];
}

// ---------------- BatchNorm (training stats over nodes) ----------------
__global__ __launch_bounds__(256) void k_bn_reduce(const float* __restrict__ h, float* __restrict__ stat) {
  float s = 0.f, s2 = 0.f;
  for (int i = blockIdx.x * 256 + threadIdx.x; i < NN * 64; i += gridDim.x * 256) {
    float v = h[i]; s += v; s2 += v * v;
  }
  __shared__ float sh[512];
  sh[threadIdx.x] = s; sh[256 + threadIdx.x] = s2;
  __syncthreads();
  if (threadIdx.x < 64) {
    int c = threadIdx.x;
    float a = sh[c] + sh[c + 64] + sh[c + 128] + sh[c + 192];
    float b = sh[256 + c] + sh[256 + c + 64] + sh[256 + c + 128] + sh[256 + c + 192];
    atomicAdd(&stat[c], a);
    atomicAdd(&stat[64 + c], b);
  }
}

__global__ void k_bn_final(const float* __restrict__ stat, const float* __restrict__ g,
                           const float* __restrict__ b, float* __restrict__ AB) {
  int c = threadIdx.x;                              // 64 threads
  float mean = stat[c] * (1.f / NN);
  float var  = stat[64 + c] * (1.f / NN) - mean * mean;
  float rstd = rsqrtf(var + 1e-5f);
  float A = g[c] * rstd;
  AB[c] = A; AB[64 + c] = b[c] - mean * A;
}

__global__ __launch_bounds__(256) void k_bn_apply(float* __restrict__ h, const float* __restrict__ AB) {
  int i = blockIdx.x * 256 + threadIdx.x;
  int c = i & 63;
  h[i] = lrelu(h[i] * AB[c] + AB[64 + c]);
}

// ---------------- split h into bf16 hi/lo (per-graph k-major) + per-node sum sq ----------------
// k-major layout: hi[((g*8 + s)*NPG + npg)*8 + e]  (s = k-chunk 0..7, e = elem 0..7)
// -> gram staging is LDS-linear AND global-coalesced simultaneously
__global__ __launch_bounds__(256) void k_split_sq(const float* __restrict__ h,
    unsigned short* __restrict__ hi, unsigned short* __restrict__ lo, float* __restrict__ sq) {
  int wv = threadIdx.x >> 6, lane = threadIdx.x & 63;
  int n = blockIdx.x * 4 + wv;
  int b = n >> 12, npg = n & (NPG - 1);
  float v = h[n * 64 + lane];
  unsigned short hu = f2bf(v);
  float hf = bf2f(hu);
  int idx = ((b * 8 + (lane >> 3)) * NPG + npg) * 8 + (lane & 7);
  hi[idx] = hu;
  lo[idx] = f2bf(v - hf);
  float s = v * v;
  #pragma unroll
  for (int d = 32; d > 0; d >>= 1) s += __shfl_xor(s, d, 64);
  if (lane == 0) sq[n] = s;
}

// ---------------- fused Gram (split-bf16 MFMA, swapped operands) + register top-k ----------------
// 64 rows/block (512 blocks), XCD swizzle graph = bid&7 (each XCD works one graph -> L2-resident).
// Double-buffered 64-cand LDS tiles; next-tile loads live only between barriers (no spill).
// Rank by key = 0.5*sq[c] - dot (monotonic in dist per row); self excluded at merge.
__global__ __launch_bounds__(256) void k_gram_topk(
    const unsigned short* __restrict__ hbhi, const unsigned short* __restrict__ hblo,
    const float* __restrict__ sq, int* __restrict__ cand) {
  __shared__ alignas(16) unsigned short Ahi[8 * 64 * 8], Alo[8 * 64 * 8];    // our 64 rows, 16 KB
  __shared__ alignas(16) unsigned short Bhi[2 * 8 * 64 * 8];                 // 2 x 64-cand tiles
  __shared__ alignas(16) unsigned short Blo[2 * 8 * 64 * 8];                 // 32 KB total B
  __shared__ float sqch[2][64];

  int tid = threadIdx.x, wv = tid >> 6, lane = tid & 63;
  int b = blockIdx.x & 7, rblk = blockIdx.x >> 3;   // XCD swizzle: graph = bid % 8
  int gbase = b * NPG, rowbase = gbase + rblk * 64;
  int l15 = lane & 15, l4 = lane >> 4;

  // stage A (64 rows): chn = s*64+row, LDS-linear + global-coalesced (k-major global)
  #pragma unroll
  for (int r = 0; r < 2; ++r) {
    int chn = tid + r * 256;
    int s = chn >> 6, row = chn & 63;
    int gi = ((b * 8 + s) * NPG + rblk * 64 + row) * 8;
    *(uint4*)&Ahi[chn * 8] = *(const uint4*)&hbhi[gi];
    *(uint4*)&Alo[chn * 8] = *(const uint4*)&hblo[gi];
  }
  // stage B tile 0 into buffer 0
  #pragma unroll
  for (int r = 0; r < 2; ++r) {
    int chn = tid + r * 256;
    int s = chn >> 6, node = chn & 63;
    int gi = ((b * 8 + s) * NPG + node) * 8;
    *(uint4*)&Bhi[chn * 8] = *(const uint4*)&hbhi[gi];
    *(uint4*)&Blo[chn * 8] = *(const uint4*)&hblo[gi];
  }
  if (tid < 64) sqch[0][tid] = 0.5f * sq[gbase + tid];
  __syncthreads();

  int rloc = wv * 16 + l15;
  int rnode = rowbase + rloc;
  // our-row fragments (loop-invariant): B-operand, row = rloc, k-chunk s = ks*4 + l4
  v8s ofh[2], ofl[2];
  #pragma unroll
  for (int ks = 0; ks < 2; ++ks) {
    int s = ks * 4 + l4;
    ofh[ks] = *(v8s*)&Ahi[(s * 64 + rloc) * 8];
    ofl[ks] = *(v8s*)&Alo[(s * 64 + rloc) * 8];
  }

  float td[10]; int ti[10];
  #pragma unroll
  for (int j = 0; j < 10; ++j) { td[j] = 1e30f; ti[j] = 0x7fffffff; }

  int cur = 0;
  for (int it = 0; it < NPG / 64; ++it) {
    // issue next tile's loads FIRST (overlap with MFMA+select; regs never cross a barrier)
    bool more = (it + 1 < NPG / 64);
    uint4 nh0, nh1, nl0, nl1;
    float nsq = 0.f;
    if (more) {
      int tb = (it + 1) * 64;
      int s0 = tid >> 6, n0 = tid & 63;
      int chn1 = tid + 256, s1 = chn1 >> 6, n1 = chn1 & 63;
      int g0 = ((b * 8 + s0) * NPG + tb + n0) * 8;
      int g1 = ((b * 8 + s1) * NPG + tb + n1) * 8;
      nh0 = *(const uint4*)&hbhi[g0];
      nh1 = *(const uint4*)&hbhi[g1];
      nl0 = *(const uint4*)&hblo[g0];
      nl1 = *(const uint4*)&hblo[g1];
      if (tid < 64) nsq = 0.5f * sq[gbase + tb + tid];
    }

    int base = cur * 512;                 // chunk units: 512 chunks (8 s x 64 nodes) per buffer
    int cb = gbase + it * 64;
    #pragma unroll
    for (int cg = 0; cg < 4; ++cg) {
      // candidate fragments: A-operand, cand = cg*16 + l15, k-chunk s = ks*4 + l4
      v8s ch0 = *(v8s*)&Bhi[(base + (0 + l4) * 64 + cg * 16 + l15) * 8];
      v8s ch1 = *(v8s*)&Bhi[(base + (4 + l4) * 64 + cg * 16 + l15) * 8];
      v8s cl0 = *(v8s*)&Blo[(base + (0 + l4) * 64 + cg * 16 + l15) * 8];
      v8s cl1 = *(v8s*)&Blo[(base + (4 + l4) * 64 + cg * 16 + l15) * 8];
      // two independent accumulator chains: hi*hi  ||  hi*lo + lo*hi
      v4f accA = {0.f, 0.f, 0.f, 0.f}, accB = {0.f, 0.f, 0.f, 0.f};
      accA = __builtin_amdgcn_mfma_f32_16x16x32_bf16(ch0, ofh[0], accA, 0, 0, 0);
      accB = __builtin_amdgcn_mfma_f32_16x16x32_bf16(ch0, ofl[0], accB, 0, 0, 0);
      accA = __builtin_amdgcn_mfma_f32_16x16x32_bf16(ch1, ofh[1], accA, 0, 0, 0);
      accB = __builtin_amdgcn_mfma_f32_16x16x32_bf16(ch1, ofl[1], accB, 0, 0, 0);
      accB = __builtin_amdgcn_mfma_f32_16x16x32_bf16(cl0, ofh[0], accB, 0, 0, 0);
      accB = __builtin_amdgcn_mfma_f32_16x16x32_bf16(cl1, ofh[1], accB, 0, 0, 0);
      // D layout: cand = l4*4 + r, our = l15 (verified); key = 0.5*sq[c] - dot
      int kb = cg * 16 + l4 * 4;
      float k0 = sqch[cur][kb + 0] - (accA[0] + accB[0]);
      float k1 = sqch[cur][kb + 1] - (accA[1] + accB[1]);
      float k2 = sqch[cur][kb + 2] - (accA[2] + accB[2]);
      float k3 = sqch[cur][kb + 3] - (accA[3] + accB[3]);
      float gmin = fminf(fminf(k0, k1), fminf(k2, k3));
      if (gmin < td[9]) {
        float kk[4] = {k0, k1, k2, k3};
        #pragma unroll
        for (int r = 0; r < 4; ++r) {
          if (kk[r] < td[9]) {
            float cd = kk[r]; int ci = cb + kb + r;
            #pragma unroll
            for (int u = 0; u < 10; ++u) {
              bool bt = cd < td[u];
              float nd = bt ? cd : td[u]; int nc = bt ? ci : ti[u];
              float od = bt ? td[u] : cd; int oc = bt ? ti[u] : ci;
              td[u] = nd; ti[u] = nc; cd = od; ci = oc;
            }
          }
        }
      }
    }

    // write prefetched tile into the other buffer, then one barrier
    if (more) {
      int nb_ = (cur ^ 1) * 4096;         // short units: 4096 shorts per buffer
      *(uint4*)&Bhi[nb_ + tid * 8]         = nh0;
      *(uint4*)&Bhi[nb_ + (tid + 256) * 8] = nh1;
      *(uint4*)&Blo[nb_ + tid * 8]         = nl0;
      *(uint4*)&Blo[nb_ + (tid + 256) * 8] = nl1;
      if (tid < 64) sqch[cur ^ 1][tid] = nsq;
    }
    __syncthreads();
    cur ^= 1;
  }

  // dump per-lane lists: row rloc has 4 lists (l4) x 10 entries -> merge scratch in B LDS
  float* mbd = (float*)Bhi;   // 64*4*10*4B = 10240 B, fits in 16 KB
  int*   mbi = (int*)Blo;
  #pragma unroll
  for (int j = 0; j < 10; ++j) {
    mbd[(rloc * 4 + l4) * 10 + j] = td[j];
    mbi[(rloc * 4 + l4) * 10 + j] = ti[j];
  }
  __syncthreads();
  if (tid < 64) {
    int rn = rowbase + tid;
    float fd[12]; int fi[12];
    #pragma unroll
    for (int j = 0; j < 12; ++j) { fd[j] = 1e30f; fi[j] = 0x7fffffff; }
    #pragma unroll 1
    for (int u = 0; u < 40; ++u) {
      float cd = mbd[tid * 40 + u];
      int   ci = mbi[tid * 40 + u];
      if (ci != rn && (cd < fd[11] || (cd == fd[11] && ci < fi[11]))) {
        #pragma unroll
        for (int v = 0; v < 12; ++v) {
          bool better = (cd < fd[v]) || (cd == fd[v] && ci < fi[v]);
          if (better) { float tf = fd[v]; int tq = fi[v]; fd[v] = cd; fi[v] = ci; cd = tf; ci = tq; }
        }
      }
    }
    #pragma unroll
    for (int j = 0; j < 12; ++j) cand[rn * 12 + j] = fi[j];
  }
}

// ---------------- exact fp32 refinement: top-8 of the 12 candidates ----------------
__global__ __launch_bounds__(256) void k_refine(
    const float* __restrict__ h, const int* __restrict__ cand, int* __restrict__ knn) {
  int wv = threadIdx.x >> 6, lane = threadIdx.x & 63;
  int n = blockIdx.x * 4 + wv;
  float hn = h[n * 64 + lane];
  float td[8]; int ti[8];
  #pragma unroll
  for (int j = 0; j < 8; ++j) { td[j] = 1e30f; ti[j] = 0x7fffffff; }
  #pragma unroll 1
  for (int j = 0; j < 12; ++j) {
    int c = cand[n * 12 + j];
    float df = h[c * 64 + lane] - hn;
    float s = df * df;
    #pragma unroll
    for (int d = 32; d > 0; d >>= 1) s += __shfl_xor(s, d, 64);
    if (s < td[7] || (s == td[7] && c < ti[7])) {
      float cd = s; int ci = c;
      #pragma unroll
      for (int u = 0; u < 8; ++u) {
        bool better = (cd < td[u]) || (cd == td[u] && ci < ti[u]);
        if (better) { float tf = td[u]; int tq = ti[u]; td[u] = cd; ti[u] = ci; cd = tf; ci = tq; }
      }
    }
  }
  #pragma unroll
  for (int u = 0; u < 8; ++u) {
    if (lane == u) knn[n * 8 + u] = ti[u];
  }
}

// ---------------- dyn-MLP prep: A = h*W1[0:64] + b1, C = h*W1[64:128]  (per node) ----------------
// y1 = lrelu(msg@W1 + b1) with msg=[h_n, h_m-h_n]  =>  y1 = lrelu(A_n + C_m - C_n)
__global__ __launch_bounds__(256) void k_dynprep(
    const float* __restrict__ h,
    const float* __restrict__ w1, const float* __restrict__ b1,
    float* __restrict__ A, float* __restrict__ C) {
  __shared__ alignas(16) float hT[64 * 20];         // [j][16 nodes], pad 20
  int t = threadIdx.x;
  int nb = blockIdx.x * 16;
  {
    int n = t >> 4, qj = t & 15;
    float4 v = *(const float4*)(h + (nb + n) * 64 + qj * 4);
    hT[(qj * 4 + 0) * 20 + n] = v.x;
    hT[(qj * 4 + 1) * 20 + n] = v.y;
    hT[(qj * 4 + 2) * 20 + n] = v.z;
    hT[(qj * 4 + 3) * 20 + n] = v.w;
  }
  __syncthreads();
  int pq = t >> 6, cq = t & 63;
  int oc = cq * 2;
  const float* wb; float* ob; int ocl; float bv0, bv1;
  if (oc < 64) { wb = w1 + oc;             ob = A; ocl = oc;      bv0 = b1[oc]; bv1 = b1[oc + 1]; }
  else         { wb = w1 + 4096 + (oc-64); ob = C; ocl = oc - 64; bv0 = 0.f;    bv1 = 0.f; }
  float acc[4][2];
  #pragma unroll
  for (int i = 0; i < 4; ++i) { acc[i][0] = bv0; acc[i][1] = bv1; }
  for (int j = 0; j < 64; ++j) {
    float4 av = *(float4*)&hT[j * 20 + pq * 4];
    float2 wv = *(const float2*)(wb + j * 64);
    acc[0][0] += av.x * wv.x; acc[0][1] += av.x * wv.y;
    acc[1][0] += av.y * wv.x; acc[1][1] += av.y * wv.y;
    acc[2][0] += av.z * wv.x; acc[2][1] += av.z * wv.y;
    acc[3][0] += av.w * wv.x; acc[3][1] += av.w * wv.y;
  }
  #pragma unroll
  for (int i = 0; i < 4; ++i) {
    int n = nb + pq * 4 + i;
    ob[n * 64 + ocl]     = acc[i][0];
    ob[n * 64 + ocl + 1] = acc[i][1];
  }
}

// ---------------- dyn-MLP aggregate: ybar = mean_k lrelu(A_n + C_m - C_n); out = ybar*W2 + b2 ----
__global__ __launch_bounds__(256) void k_dynagg(
    const float* __restrict__ A, const float* __restrict__ C,
    const int* __restrict__ knn, const float* __restrict__ w2,
    const float* __restrict__ b2, float* __restrict__ out) {
  __shared__ float w2sh[64 * 64];                   // 16 KB, linear (2-way bank alias = free)
  __shared__ float ysh[4 * 64];
  int t = threadIdx.x, wv = t >> 6, lane = t & 63;
  int n = blockIdx.x * 4 + wv;
  for (int u = t; u < 1024; u += 256) *(float4*)&w2sh[u * 4] = *(const float4*)&w2[u * 4];
  float a  = A[n * 64 + lane];
  float cn = C[n * 64 + lane];
  int mm[8];
  #pragma unroll
  for (int k = 0; k < 8; ++k) mm[k] = knn[n * 8 + k];
  float cm[8];
  #pragma unroll
  for (int k = 0; k < 8; ++k) cm[k] = C[mm[k] * 64 + lane];   // 8 gathers in flight
  float bse = a - cn;
  float s = 0.f;
  #pragma unroll
  for (int k = 0; k < 8; ++k) s += lrelu(bse + cm[k]);
  ysh[wv * 64 + lane] = s * 0.125f;
  __syncthreads();
  float acc = b2[lane];
  for (int j = 0; j < 64; j += 4) {
    float y0 = ysh[wv * 64 + j],     y1 = ysh[wv * 64 + j + 1];
    float y2 = ysh[wv * 64 + j + 2], y3 = ysh[wv * 64 + j + 3];
    acc += y0 * w2sh[j * 64 + lane]       + y1 * w2sh[(j + 1) * 64 + lane]
         + y2 * w2sh[(j + 2) * 64 + lane] + y3 * w2sh[(j + 3) * 64 + lane];
  }
  out[n * 64 + lane] = acc;
}

// ---------------- GAT2 node transforms (in-dim 64, l+r fused) ----------------
__global__ __launch_bounds__(256) void k_xform64(
    const float* __restrict__ h,
    const float* __restrict__ wl, const float* __restrict__ bl,
    const float* __restrict__ wr, const float* __restrict__ br,
    float* __restrict__ xl, float* __restrict__ xr) {
  __shared__ alignas(16) float hT[64 * 20];         // [j][16 nodes], pad 20
  int t = threadIdx.x;
  int nb = blockIdx.x * 16;
  {
    int n = t >> 4, qj = t & 15;
    float4 v = *(const float4*)(h + (nb + n) * 64 + qj * 4);
    hT[(qj * 4 + 0) * 20 + n] = v.x;
    hT[(qj * 4 + 1) * 20 + n] = v.y;
    hT[(qj * 4 + 2) * 20 + n] = v.z;
    hT[(qj * 4 + 3) * 20 + n] = v.w;
  }
  __syncthreads();
  int pq = t >> 6, cq = t & 63;
  int oc = cq * 4;
  const float* wb; const float* bb; float* ob; int ocl;
  if (oc < 128) { wb = wl + oc;         bb = bl + oc;         ob = xl; ocl = oc; }
  else          { wb = wr + (oc - 128); bb = br + (oc - 128); ob = xr; ocl = oc - 128; }
  float acc[4][4];
  #pragma unroll
  for (int c = 0; c < 4; ++c) {
    float bv = bb[c];
    #pragma unroll
    for (int i = 0; i < 4; ++i) acc[i][c] = bv;
  }
  for (int j = 0; j < 64; ++j) {
    float4 av = *(float4*)&hT[j * 20 + pq * 4];
    float4 wv = *(const float4*)(wb + j * 128);
    float aa[4] = {av.x, av.y, av.z, av.w};
    float ww[4] = {wv.x, wv.y, wv.z, wv.w};
    #pragma unroll
    for (int i = 0; i < 4; ++i)
      #pragma unroll
      for (int c = 0; c < 4; ++c) acc[i][c] += aa[i] * ww[c];
  }
  #pragma unroll
  for (int i = 0; i < 4; ++i) {
    int n = nb + pq * 4 + i;
    #pragma unroll
    for (int c = 0; c < 4; ++c) ob[n * 128 + ocl + c] = acc[i][c];
  }
}

// ---------------- attention-pool gate per node ----------------
__global__ __launch_bounds__(256) void k_gate(
    const float* __restrict__ h3, const float* __restrict__ w1, const float* __restrict__ b1,
    const float* __restrict__ w2, const float* __restrict__ b2, float* __restrict__ gates) {
  __shared__ float hsh[4][64];
  int wv = threadIdx.x >> 6, lane = threadIdx.x & 63;
  int n = blockIdx.x * 4 + wv;
  hsh[wv][lane] = h3[n * 64 + lane];
  __syncthreads();
  float s = b1[lane];
  for (int j = 0; j < 64; ++j) s += hsh[wv][j] * w1[j * 64 + lane];
  float tv = tanhf(s) * w2[lane];
  #pragma unroll
  for (int d = 32; d > 0; d >>= 1) tv += __shfl_xor(tv, d, 64);
  if (lane == 0) gates[n] = tv + b2[0];
}

// ---------------- per-graph softmax pool ----------------
__global__ __launch_bounds__(1024) void k_pool(
    const float* __restrict__ gates, const float* __restrict__ h3,
    float* __restrict__ pexp, float* __restrict__ gpool) {
  int b = blockIdx.x, t = threadIdx.x;
  const float* g = gates + b * NPG;
  __shared__ float red[1024];
  float m = -1e30f;
  for (int i = t; i < NPG; i += 1024) m = fmaxf(m, g[i]);
  red[t] = m; __syncthreads();
  for (int s = 512; s > 0; s >>= 1) { if (t < s) red[t] = fmaxf(red[t], red[t + s]); __syncthreads(); }
  m = red[0]; __syncthreads();
  float sum = 0.f;
  for (int i = t; i < NPG; i += 1024) { float p = __expf(g[i] - m); pexp[b * NPG + i] = p; sum += p; }
  red[t] = sum; __syncthreads();
  for (int s = 512; s > 0; s >>= 1) { if (t < s) red[t] += red[t + s]; __syncthreads(); }
  float den = red[0];
  __syncthreads();
  int grp = t >> 6, c = t & 63;
  float acc = 0.f;
  for (int i = grp; i < NPG; i += 16) acc += pexp[b * NPG + i] * h3[(b * NPG + i) * 64 + c];
  red[t] = acc; __syncthreads();
  if (t < 64) {
    float a = 0.f;
    for (int qq = 0; qq < 16; ++qq) a += red[qq * 64 + t];
    gpool[b * 64 + t] = a / den;
  }
}

// ---------------- context MLP (tiny) ----------------
__global__ void k_ctx(const float* __restrict__ gpool,
                      const float* __restrict__ w1, const float* __restrict__ b1,
                      const float* __restrict__ w2, const float* __restrict__ b2,
                      float* __restrict__ gctx) {
  __shared__ float gsh[64], tsh[64];
  int b = blockIdx.x, c = threadIdx.x;              // 64 threads
  gsh[c] = gpool[b * 64 + c];
  __syncthreads();
  float s = b1[c];
  for (int j = 0; j < 64; ++j) s += gsh[j] * w1[j * 64 + c];
  tsh[c] = lrelu(s);
  __syncthreads();
  float o = b2[c];
  for (int j = 0; j < 64; ++j) o += tsh[j] * w2[j * 64 + c];
  gctx[b * 64 + c] = o;
}

// ---------------- fused decoder: 133->128 -> LN -> 64 -> 3, +x, tanh*CAP ----------------
__global__ __launch_bounds__(128) void k_decoder(
    const float* __restrict__ h3, const float* __restrict__ gctx, const float* __restrict__ x,
    const float* __restrict__ w1, const float* __restrict__ b1,
    const float* __restrict__ lng, const float* __restrict__ lnb,
    const float* __restrict__ w2, const float* __restrict__ b2,
    const float* __restrict__ w3, const float* __restrict__ b3,
    float* __restrict__ out) {
  __shared__ alignas(16) float hf[16 * 136];
  __shared__ alignas(16) float dT[16 * 132];
  __shared__ float d2[16 * 65];
  __shared__ float mu[16], rs[16];
  int t = threadIdx.x;
  int nb = blockIdx.x * 16;
  int gb = nb >> 12;
  for (int u = t; u < 16 * 64; u += 128) { int p = u >> 6, j = u & 63; hf[p * 136 + j] = h3[(nb + p) * 64 + j]; }
  for (int u = t; u < 16 * 64; u += 128) { int p = u >> 6, j = u & 63; hf[p * 136 + 64 + j] = gctx[gb * 64 + j]; }
  for (int u = t; u < 16 * 5; u += 128) { int p = u / 5, j = u % 5; hf[p * 136 + 128 + j] = x[(nb + p) * 5 + j]; }
  __syncthreads();
  float acc[16];
  #pragma unroll
  for (int p = 0; p < 16; ++p) acc[p] = b1[t];
  for (int j4 = 0; j4 < 128; j4 += 4) {
    float w0 = w1[(j4 + 0) * 128 + t], wv1 = w1[(j4 + 1) * 128 + t];
    float wv2 = w1[(j4 + 2) * 128 + t], wv3 = w1[(j4 + 3) * 128 + t];
    #pragma unroll
    for (int p = 0; p < 16; ++p) {
      float4 hv = *(float4*)&hf[p * 136 + j4];
      acc[p] += hv.x * w0 + hv.y * wv1 + hv.z * wv2 + hv.w * wv3;
    }
  }
  for (int j = 128; j < 133; ++j) {
    float w = w1[j * 128 + t];
    #pragma unroll
    for (int p = 0; p < 16; ++p) acc[p] += hf[p * 136 + j] * w;
  }
  #pragma unroll
  for (int p = 0; p < 16; ++p) dT[p * 132 + t] = lrelu(acc[p]);
  __syncthreads();
  if (t < 16) {
    float s = 0.f, s2 = 0.f;
    for (int j = 0; j < 128; ++j) { float v = dT[t * 132 + j]; s += v; s2 += v * v; }
    float mn = s * (1.f / 128.f);
    float vr = s2 * (1.f / 128.f) - mn * mn;
    mu[t] = mn; rs[t] = rsqrtf(vr + 1e-5f);
  }
  __syncthreads();
  float lg = lng[t], lb = lnb[t];
  #pragma unroll
  for (int p = 0; p < 16; ++p) dT[p * 132 + t] = (dT[p * 132 + t] - mu[p]) * rs[p] * lg + lb;
  __syncthreads();
  if (t < 64) {
    float a2[16];
    #pragma unroll
    for (int p = 0; p < 16; ++p) a2[p] = b2[t];
    for (int j4 = 0; j4 < 128; j4 += 4) {
      float w0 = w2[(j4 + 0) * 64 + t], wv1 = w2[(j4 + 1) * 64 + t];
      float wv2 = w2[(j4 + 2) * 64 + t], wv3 = w2[(j4 + 3) * 64 + t];
      #pragma unroll
      for (int p = 0; p < 16; ++p) {
        float4 dv = *(float4*)&dT[p * 132 + j4];
        a2[p] += dv.x * w0 + dv.y * wv1 + dv.z * wv2 + dv.w * wv3;
      }
    }
    #pragma unroll
    for (int p = 0; p < 16; ++p) d2[p * 65 + t] = lrelu(a2[p]);
  }
  __syncthreads();
  if (t < 48) {
    int p = t / 3, k = t % 3;
    float o = b3[k];
    for (int j = 0; j < 64; ++j) o += d2[p * 65 + j] * w3[j * 3 + k];
    out[(nb + p) * 3 + k] = x[(nb + p) * 5 + k] + tanhf(o) * 20.0f;
  }
}

// ---------------- workspace layout (bytes) ----------------
// [0, 16MB): kNN-phase (hbhi, hblo, sq, knn); A overwrites hbhi/hblo after gram; xl2 later
#define O_XL     0ul
#define O_HBHI   0ul
#define O_A      0ul           // 8 MB, after gram_topk (hbhi/hblo dead)
#define O_HBLO   4194304ul
#define O_SQ     8388608ul
#define O_KNN    8519680ul
// [16MB, 32MB): cand during kNN; C overwrites cand after refine; xr2 later
#define O_XR     16777216ul
#define O_CAND   16777216ul
#define O_C      16777216ul    // 8 MB
#define O_H1     33554432ul    // 8 MB: GAT1 out -> h1 -> (GAT2 out -> h3)
#define O_H2     41943040ul    // 8 MB: dynagg out -> h2
#define O_CNT    50331648ul
#define O_START  50462720ul
#define O_CUR    50593792ul
#define O_BKT    50724864ul    // edge ids by bucket order (2 MB)
#define O_BSRC   52822016ul    // src node  by bucket order (2 MB)
#define O_STAT   54919168ul
#define O_AB     54919680ul
#define O_GATES  54920192ul
#define O_PEXP   55051264ul
#define O_GPOOL  55182336ul
#define O_GCTX   55184384ul

extern "C" void kernel_launch(void* const* d_in, const int* in_sizes, int n_in,
                              void* d_out, int out_size, void* d_ws, size_t ws_size,
                              hipStream_t stream) {
  (void)in_sizes; (void)n_in; (void)out_size; (void)ws_size;
  const float* x      = (const float*)d_in[0];
  const float* eattr  = (const float*)d_in[1];
  const int*   ei     = (const int*)d_in[2];
  const float* g1_wl  = (const float*)d_in[3];
  const float* g1_bl  = (const float*)d_in[4];
  const float* g1_wr  = (const float*)d_in[5];
  const float* g1_br  = (const float*)d_in[6];
  const float* g1_we  = (const float*)d_in[7];
  const float* g1_att = (const float*)d_in[8];
  const float* g1_bias= (const float*)d_in[9];
  const float* bn1_g  = (const float*)d_in[10];
  const float* bn1_b  = (const float*)d_in[11];
  const float* em_w1  = (const float*)d_in[12];
  const float* em_b1  = (const float*)d_in[13];
  const float* em_w2  = (const float*)d_in[14];
  const float* em_b2  = (const float*)d_in[15];
  const float* bn2_g  = (const float*)d_in[16];
  const float* bn2_b  = (const float*)d_in[17];
  const float* g2_wl  = (const float*)d_in[18];
  const float* g2_bl  = (const float*)d_in[19];
  const float* g2_wr  = (const float*)d_in[20];
  const float* g2_br  = (const float*)d_in[21];
  const float* g2_att = (const float*)d_in[22];
  const float* g2_bias= (const float*)d_in[23];
  const float* bn3_g  = (const float*)d_in[24];
  const float* bn3_b  = (const float*)d_in[25];
  const float* gt_w1  = (const float*)d_in[26];
  const float* gt_b1  = (const float*)d_in[27];
  const float* gt_w2  = (const float*)d_in[28];
  const float* gt_b2  = (const float*)d_in[29];
  const float* cx_w1  = (const float*)d_in[30];
  const float* cx_b1  = (const float*)d_in[31];
  const float* cx_w2  = (const float*)d_in[32];
  const float* cx_b2  = (const float*)d_in[33];
  const float* dc_w1  = (const float*)d_in[34];
  const float* dc_b1  = (const float*)d_in[35];
  const float* ln_g   = (const float*)d_in[36];
  const float* ln_b   = (const float*)d_in[37];
  const float* dc_w2  = (const float*)d_in[38];
  const float* dc_b2  = (const float*)d_in[39];
  const float* dc_w3  = (const float*)d_in[40];
  const float* dc_b3  = (const float*)d_in[41];

  char* ws = (char*)d_ws;
  float* xl    = (float*)(ws + O_XL);
  float* xr    = (float*)(ws + O_XR);
  float* h1    = (float*)(ws + O_H1);
  float* h2    = (float*)(ws + O_H2);
  int*   cnt   = (int*)(ws + O_CNT);
  int*   start = (int*)(ws + O_START);
  int*   cur   = (int*)(ws + O_CUR);
  int*   bkt   = (int*)(ws + O_BKT);
  int*   bsrc  = (int*)(ws + O_BSRC);
  unsigned short* hbhi = (unsigned short*)(ws + O_HBHI);
  unsigned short* hblo = (unsigned short*)(ws + O_HBLO);
  float* sq    = (float*)(ws + O_SQ);
  int*   knn   = (int*)(ws + O_KNN);
  int*   cand  = (int*)(ws + O_CAND);
  float* Aar   = (float*)(ws + O_A);
  float* Car   = (float*)(ws + O_C);
  float* stat  = (float*)(ws + O_STAT);
  float* AB    = (float*)(ws + O_AB);
  float* gates = (float*)(ws + O_GATES);
  float* pexp  = (float*)(ws + O_PEXP);
  float* gpool = (float*)(ws + O_GPOOL);
  float* gctx  = (float*)(ws + O_GCTX);

  const int* src = ei;
  const int* dst = ei + NE;

  // ---- GAT layer 1 ----
  hipMemsetAsync(cnt, 0, NN * 4, stream);
  k_xform5<<<NN * 128 / 256, 256, 0, stream>>>(x, g1_wl, g1_bl, g1_wr, g1_br, xl, xr);
  k_count<<<NE / 256, 256, 0, stream>>>(dst, cnt);
  k_scan<<<1, 1024, 0, stream>>>(cnt, start, cur);
  k_scatter<<<NE / 256, 256, 0, stream>>>(dst, src, cur, bkt, bsrc);
  k_gat_edge<1><<<NN / 4, 256, 0, stream>>>(xl, xr, eattr, g1_we, g1_att, g1_bias,
                                            start, cnt, bsrc, bkt, h1);
  hipMemsetAsync(stat, 0, 512, stream);
  k_bn_reduce<<<256, 256, 0, stream>>>(h1, stat);
  k_bn_final<<<1, 64, 0, stream>>>(stat, bn1_g, bn1_b, AB);
  k_bn_apply<<<NN * 64 / 256, 256, 0, stream>>>(h1, AB);

  // ---- dynamic kNN (approx MFMA gram + exact fp32 refine) + separable edge MLP ----
  k_split_sq<<<NN / 4, 256, 0, stream>>>(h1, hbhi, hblo, sq);
  k_gram_topk<<<NGR * (NPG / 64), 256, 0, stream>>>(hbhi, hblo, sq, cand);
  k_refine<<<NN / 4, 256, 0, stream>>>(h1, cand, knn);
  k_dynprep<<<NN / 16, 256, 0, stream>>>(h1, em_w1, em_b1, Aar, Car);   // A over hbhi/hblo, C over cand
  k_dynagg<<<NN / 4, 256, 0, stream>>>(Aar, Car, knn, em_w2, em_b2, h2);
  hipMemsetAsync(stat, 0, 512, stream);
  k_bn_reduce<<<256, 256, 0, stream>>>(h2, stat);
  k_bn_final<<<1, 64, 0, stream>>>(stat, bn2_g, bn2_b, AB);
  k_bn_apply<<<NN * 64 / 256, 256, 0, stream>>>(h2, AB);

  // ---- GAT layer 2 ----
  k_xform64<<<NN / 16, 256, 0, stream>>>(h2, g2_wl, g2_bl, g2_wr, g2_br, xl, xr);
  k_gat_edge<0><<<NN / 4, 256, 0, stream>>>(xl, xr, nullptr, nullptr, g2_att, g2_bias,
                                            start, cnt, bsrc, bkt, h1);
  hipMemsetAsync(stat, 0, 512, stream);
  k_bn_reduce<<<256, 256, 0, stream>>>(h1, stat);
  k_bn_final<<<1, 64, 0, stream>>>(stat, bn3_g, bn3_b, AB);
  k_bn_apply<<<NN * 64 / 256, 256, 0, stream>>>(h1, AB);   // h1 is now h3

  // ---- pooling + context ----
  k_gate<<<NN / 4, 256, 0, stream>>>(h1, gt_w1, gt_b1, gt_w2, gt_b2, gates);
  k_pool<<<NGR, 1024, 0, stream>>>(gates, h1, pexp, gpool);
  k_ctx<<<NGR, 64, 0, stream>>>(gpool, cx_w1, cx_b1, cx_w2, cx_b2, gctx);

  // ---- decoder ----
  k_decoder<<<NN / 16, 128, 0, stream>>>(h1, gctx, x, dc_w1, dc_b1, ln_g, ln_b,
                                         dc_w2, dc_b2, dc_w3, dc_b3, (float*)d_out);
}

// Round 11
// 1012.816 us; speedup vs baseline: 1.3651x; 1.0150x over previous
//
#include <hip/hip_runtime.h>

#define NN   32768
#define NPG  4096
#define NGR  8
#define NE   524288
#define NEGS 0.2f

typedef float  v4f __attribute__((ext_vector_type(4)));
typedef short  v8s __attribute__((ext_vector_type(8)));

__device__ __forceinline__ float lrelu(float x){ return x > 0.f ? x : NEGS*x; }

// round-to-nearest-even fp32 -> bf16 (bit trick; inputs are finite)
__device__ __forceinline__ unsigned short f2bf(float v){
  unsigned int u = __float_as_uint(v);
  u = u + 0x7fffu + ((u >> 16) & 1u);
  return (unsigned short)(u >> 16);
}
__device__ __forceinline__ float bf2f(unsigned short s){
  return __uint_as_float(((unsigned int)s) << 16);
}

// ---------------- GAT1 node transforms (in-dim 5) ----------------
__global__ __launch_bounds__(256) void k_xform5(
    const float* __restrict__ x,
    const float* __restrict__ wl, const float* __restrict__ bl,
    const float* __restrict__ wr, const float* __restrict__ br,
    float* __restrict__ xl, float* __restrict__ xr) {
  int t = blockIdx.x * 256 + threadIdx.x;          // NN*128 threads
  int n = t >> 7, oc = t & 127;
  const float* xp = x + n * 5;
  float a = bl[oc], b = br[oc];
  #pragma unroll
  for (int j = 0; j < 5; ++j) {
    float v = xp[j];
    a += v * wl[j * 128 + oc];
    b += v * wr[j * 128 + oc];
  }
  xl[t] = a; xr[t] = b;
}

// ---------------- CSR build (bucket edges by dst) ----------------
__global__ __launch_bounds__(256) void k_count(const int* __restrict__ dst, int* __restrict__ cnt) {
  int e = blockIdx.x * 256 + threadIdx.x;
  atomicAdd(&cnt[dst[e]], 1);
}

__global__ __launch_bounds__(1024) void k_scan(const int* __restrict__ cnt,
                                               int* __restrict__ start, int* __restrict__ cur) {
  __shared__ int sh[1024];
  int t = threadIdx.x;
  int base = t * 32;
  int s = 0;
  for (int i = 0; i < 32; ++i) s += cnt[base + i];
  sh[t] = s;
  __syncthreads();
  for (int ofs = 1; ofs < 1024; ofs <<= 1) {
    int v = (t >= ofs) ? sh[t - ofs] : 0;
    __syncthreads();
    sh[t] += v;
    __syncthreads();
  }
  int run = sh[t] - s;                              // exclusive prefix
  for (int i = 0; i < 32; ++i) {
    start[base + i] = run; cur[base + i] = run;
    run += cnt[base + i];
  }
}

__global__ __launch_bounds__(256) void k_scatter(const int* __restrict__ dst,
                                                 const int* __restrict__ srcv,
                                                 int* __restrict__ cur,
                                                 int* __restrict__ bkt_e, int* __restrict__ bkt_s) {
  int e = blockIdx.x * 256 + threadIdx.x;
  int p = atomicAdd(&cur[dst[e]], 1);
  bkt_e[p] = e;
  bkt_s[p] = srcv[e];
}

// ---------------- GATv2 edge pass: one wave per dst node, online softmax,
// 2-edge pairing (4 interleaved reduce trees, one rescale per pair) + 1-pair prefetch ----
template<int HAS_EA>
__global__ __launch_bounds__(256) void k_gat_edge(
    const float* __restrict__ xl, const float* __restrict__ xr,
    const float* __restrict__ ea,
    const float* __restrict__ we, const float* __restrict__ att,
    const float* __restrict__ bias,
    const int* __restrict__ start, const int* __restrict__ cnt,
    const int* __restrict__ bsrc, const int* __restrict__ bedge,
    float* __restrict__ out) {
  int wv = threadIdx.x >> 6, lane = threadIdx.x & 63;
  int n = blockIdx.x * 4 + wv;
  int s0 = start[n], deg = cnt[n];
  float xr0 = xr[n * 128 + lane], xr1 = xr[n * 128 + 64 + lane];
  float a0 = att[lane], a1 = att[64 + lane];
  float w0r[6], w1r[6];
  if (HAS_EA) {
    #pragma unroll
    for (int j = 0; j < 6; ++j) { w0r[j] = we[j * 128 + lane]; w1r[j] = we[j * 128 + 64 + lane]; }
  }
  float m0 = -1e30f, m1 = -1e30f, d0 = 0.f, d1 = 0.f, o0 = 0.f, o1 = 0.f;

  int np = deg >> 1;
  float A0 = 0.f, A1 = 0.f, B0 = 0.f, B1 = 0.f;
  float NA0 = 0.f, NA1 = 0.f, NB0 = 0.f, NB1 = 0.f;
  float EA[6], EB[6], NEA[6], NEB[6];
  if (np > 0) {
    int sa = bsrc[s0], sb = bsrc[s0 + 1];
    A0 = xl[sa * 128 + lane]; A1 = xl[sa * 128 + 64 + lane];
    B0 = xl[sb * 128 + lane]; B1 = xl[sb * 128 + 64 + lane];
    if (HAS_EA) {
      int eai = bedge[s0], ebi = bedge[s0 + 1];
      #pragma unroll
      for (int j = 0; j < 6; ++j) { EA[j] = ea[eai * 6 + j]; EB[j] = ea[ebi * 6 + j]; }
    }
  }

  for (int p = 0; p < np; ++p) {
    if (p + 1 < np) {
      int i2 = s0 + 2 * (p + 1);
      int sa = bsrc[i2], sb = bsrc[i2 + 1];
      NA0 = xl[sa * 128 + lane]; NA1 = xl[sa * 128 + 64 + lane];
      NB0 = xl[sb * 128 + lane]; NB1 = xl[sb * 128 + 64 + lane];
      if (HAS_EA) {
        int eai = bedge[i2], ebi = bedge[i2 + 1];
        #pragma unroll
        for (int j = 0; j < 6; ++j) { NEA[j] = ea[eai * 6 + j]; NEB[j] = ea[ebi * 6 + j]; }
      }
    }
    float e0a = A0 + xr0, e1a = A1 + xr1, e0b = B0 + xr0, e1b = B1 + xr1;
    if (HAS_EA) {
      float pa0 = 0.f, pa1 = 0.f, pb0 = 0.f, pb1 = 0.f;
      #pragma unroll
      for (int j = 0; j < 6; ++j) {
        pa0 += EA[j] * w0r[j]; pa1 += EA[j] * w1r[j];
        pb0 += EB[j] * w0r[j]; pb1 += EB[j] * w1r[j];
      }
      e0a += pa0; e1a += pa1; e0b += pb0; e1b += pb1;
    }
    e0a = lrelu(e0a); e1a = lrelu(e1a); e0b = lrelu(e0b); e1b = lrelu(e1b);
    float ta0 = e0a * a0, ta1 = e1a * a1, tb0 = e0b * a0, tb1 = e1b * a1;
    #pragma unroll
    for (int d = 32; d > 0; d >>= 1) {
      ta0 += __shfl_xor(ta0, d, 64); ta1 += __shfl_xor(ta1, d, 64);
      tb0 += __shfl_xor(tb0, d, 64); tb1 += __shfl_xor(tb1, d, 64);
    }
    // head 0: paired online-softmax update
    float tm0 = fmaxf(ta0, tb0);
    if (tm0 > m0) { float r = __expf(m0 - tm0); o0 *= r; d0 *= r; m0 = tm0; }
    float pa = __expf(ta0 - m0), pb = __expf(tb0 - m0);
    d0 += pa + pb; o0 += pa * A0 + pb * B0;
    // head 1
    float tm1 = fmaxf(ta1, tb1);
    if (tm1 > m1) { float r = __expf(m1 - tm1); o1 *= r; d1 *= r; m1 = tm1; }
    float qa = __expf(ta1 - m1), qb = __expf(tb1 - m1);
    d1 += qa + qb; o1 += qa * A1 + qb * B1;
    // rotate prefetch buffers
    A0 = NA0; A1 = NA1; B0 = NB0; B1 = NB1;
    if (HAS_EA) {
      #pragma unroll
      for (int j = 0; j < 6; ++j) { EA[j] = NEA[j]; EB[j] = NEB[j]; }
    }
  }

  if (deg & 1) {                                    // tail edge
    int i = s0 + deg - 1;
    int s = bsrc[i];
    float l0 = xl[s * 128 + lane], l1 = xl[s * 128 + 64 + lane];
    float e0 = l0 + xr0, e1 = l1 + xr1;
    if (HAS_EA) {
      int e = bedge[i];
      float p0 = 0.f, p1 = 0.f;
      #pragma unroll
      for (int j = 0; j < 6; ++j) { float v = ea[e * 6 + j]; p0 += v * w0r[j]; p1 += v * w1r[j]; }
      e0 += p0; e1 += p1;
    }
    e0 = lrelu(e0); e1 = lrelu(e1);
    float t0 = e0 * a0, t1 = e1 * a1;
    #pragma unroll
    for (int d = 32; d > 0; d >>= 1) { t0 += __shfl_xor(t0, d, 64); t1 += __shfl_xor(t1, d, 64); }
    if (t0 > m0) { float r = __expf(m0 - t0); o0 *= r; d0 *= r; m0 = t0; }
    float p0e = __expf(t0 - m0); d0 += p0e; o0 += p0e * l0;
    if (t1 > m1) { float r = __expf(m1 - t1); o1 *= r; d1 *= r; m1 = t1; }
    float p1e = __expf(t1 - m1); d1 += p1e; o1 += p1e * l1;
  }

  float r0 = o0 / (d0 + 1e-16f);
  float r1 = o1 / (d1 + 1e-16f);
  out[n * 64 + lane] = 0.5f * (r0 + r1) + bias[lane];
}

// ---------------- BatchNorm reduce (training stats over nodes) ----------------
__global__ __launch_bounds__(256) void k_bn_reduce(const float* __restrict__ h, float* __restrict__ stat) {
  float s = 0.f, s2 = 0.f;
  for (int i = blockIdx.x * 256 + threadIdx.x; i < NN * 64; i += gridDim.x * 256) {
    float v = h[i]; s += v; s2 += v * v;
  }
  __shared__ float sh[512];
  sh[threadIdx.x] = s; sh[256 + threadIdx.x] = s2;
  __syncthreads();
  if (threadIdx.x < 64) {
    int c = threadIdx.x;
    float a = sh[c] + sh[c + 64] + sh[c + 128] + sh[c + 192];
    float b = sh[256 + c] + sh[256 + c + 64] + sh[256 + c + 128] + sh[256 + c + 192];
    atomicAdd(&stat[c], a);
    atomicAdd(&stat[64 + c], b);
  }
}

__device__ __forceinline__ void bn_make_AB(const float* __restrict__ stat,
                                           const float* __restrict__ g,
                                           const float* __restrict__ bb,
                                           float* AB, int t) {
  if (t < 64) {
    float mean = stat[t] * (1.f / NN);
    float var  = stat[64 + t] * (1.f / NN) - mean * mean;
    float A = g[t] * rsqrtf(var + 1e-5f);
    AB[t] = A; AB[64 + t] = bb[t] - mean * A;
  }
}

// ---------------- BN apply (bn_final folded in) ----------------
__global__ __launch_bounds__(256) void k_bn_applyf(
    float* __restrict__ h, const float* __restrict__ stat,
    const float* __restrict__ g, const float* __restrict__ bb) {
  __shared__ float AB[128];
  int t = threadIdx.x;
  bn_make_AB(stat, g, bb, AB, t);
  __syncthreads();
  int i = blockIdx.x * 256 + t;
  int c = i & 63;
  h[i] = lrelu(h[i] * AB[c] + AB[64 + c]);
}

// ---------------- BN apply + bf16 hi/lo split + sum-sq (layer 1) ----------------
__global__ __launch_bounds__(256) void k_bn_apply_split(
    float* __restrict__ h, const float* __restrict__ stat,
    const float* __restrict__ g, const float* __restrict__ bb,
    unsigned short* __restrict__ hi, unsigned short* __restrict__ lo,
    float* __restrict__ sq) {
  __shared__ float AB[128];
  int t = threadIdx.x;
  bn_make_AB(stat, g, bb, AB, t);
  __syncthreads();
  int wv = t >> 6, lane = t & 63;
  int n = blockIdx.x * 4 + wv;
  int b = n >> 12, npg = n & (NPG - 1);
  float v = lrelu(h[n * 64 + lane] * AB[lane] + AB[64 + lane]);
  h[n * 64 + lane] = v;
  unsigned short hu = f2bf(v);
  float hf = bf2f(hu);
  int idx = ((b * 8 + (lane >> 3)) * NPG + npg) * 8 + (lane & 7);
  hi[idx] = hu;
  lo[idx] = f2bf(v - hf);
  float s = v * v;
  #pragma unroll
  for (int d = 32; d > 0; d >>= 1) s += __shfl_xor(s, d, 64);
  if (lane == 0) sq[n] = s;
}

// ---------------- BN apply + attention-pool gate (layer 3) ----------------
__global__ __launch_bounds__(256) void k_bn_apply_gate(
    float* __restrict__ h, const float* __restrict__ stat,
    const float* __restrict__ g, const float* __restrict__ bb,
    const float* __restrict__ gw1, const float* __restrict__ gb1,
    const float* __restrict__ gw2, const float* __restrict__ gb2,
    float* __restrict__ gates) {
  __shared__ float AB[128];
  __shared__ float hsh[4][64];
  int t = threadIdx.x;
  bn_make_AB(stat, g, bb, AB, t);
  __syncthreads();
  int wv = t >> 6, lane = t & 63;
  int n = blockIdx.x * 4 + wv;
  float v = lrelu(h[n * 64 + lane] * AB[lane] + AB[64 + lane]);
  h[n * 64 + lane] = v;
  hsh[wv][lane] = v;
  __syncthreads();
  float s = gb1[lane];
  for (int j = 0; j < 64; ++j) s += hsh[wv][j] * gw1[j * 64 + lane];
  float tv = tanhf(s) * gw2[lane];
  #pragma unroll
  for (int d = 32; d > 0; d >>= 1) tv += __shfl_xor(tv, d, 64);
  if (lane == 0) gates[n] = tv + gb2[0];
}

// ---------------- fused Gram (split-bf16 MFMA, swapped operands) + register top-k ----------------
// 64 rows/block (512 blocks), XCD swizzle graph = bid&7; double-buffered 64-cand LDS tiles;
// key = 0.5*sq[c] - dot (monotonic); per-lane top-10 -> merge top-12 of 40; self excl at merge.
__global__ __launch_bounds__(256) void k_gram_topk(
    const unsigned short* __restrict__ hbhi, const unsigned short* __restrict__ hblo,
    const float* __restrict__ sq, int* __restrict__ cand) {
  __shared__ alignas(16) unsigned short Ahi[8 * 64 * 8], Alo[8 * 64 * 8];    // our 64 rows, 16 KB
  __shared__ alignas(16) unsigned short Bhi[2 * 8 * 64 * 8];                 // 2 x 64-cand tiles
  __shared__ alignas(16) unsigned short Blo[2 * 8 * 64 * 8];
  __shared__ float sqch[2][64];

  int tid = threadIdx.x, wv = tid >> 6, lane = tid & 63;
  int b = blockIdx.x & 7, rblk = blockIdx.x >> 3;   // XCD swizzle: graph = bid % 8
  int gbase = b * NPG, rowbase = gbase + rblk * 64;
  int l15 = lane & 15, l4 = lane >> 4;

  #pragma unroll
  for (int r = 0; r < 2; ++r) {
    int chn = tid + r * 256;
    int s = chn >> 6, row = chn & 63;
    int gi = ((b * 8 + s) * NPG + rblk * 64 + row) * 8;
    *(uint4*)&Ahi[chn * 8] = *(const uint4*)&hbhi[gi];
    *(uint4*)&Alo[chn * 8] = *(const uint4*)&hblo[gi];
  }
  #pragma unroll
  for (int r = 0; r < 2; ++r) {
    int chn = tid + r * 256;
    int s = chn >> 6, node = chn & 63;
    int gi = ((b * 8 + s) * NPG + node) * 8;
    *(uint4*)&Bhi[chn * 8] = *(const uint4*)&hbhi[gi];
    *(uint4*)&Blo[chn * 8] = *(const uint4*)&hblo[gi];
  }
  if (tid < 64) sqch[0][tid] = 0.5f * sq[gbase + tid];
  __syncthreads();

  int rloc = wv * 16 + l15;
  v8s ofh[2], ofl[2];
  #pragma unroll
  for (int ks = 0; ks < 2; ++ks) {
    int s = ks * 4 + l4;
    ofh[ks] = *(v8s*)&Ahi[(s * 64 + rloc) * 8];
    ofl[ks] = *(v8s*)&Alo[(s * 64 + rloc) * 8];
  }

  float td[10]; int ti[10];
  #pragma unroll
  for (int j = 0; j < 10; ++j) { td[j] = 1e30f; ti[j] = 0x7fffffff; }

  int cur = 0;
  for (int it = 0; it < NPG / 64; ++it) {
    bool more = (it + 1 < NPG / 64);
    uint4 nh0, nh1, nl0, nl1;
    float nsq = 0.f;
    if (more) {
      int tb = (it + 1) * 64;
      int s0 = tid >> 6, n0 = tid & 63;
      int chn1 = tid + 256, s1 = chn1 >> 6, n1 = chn1 & 63;
      int g0 = ((b * 8 + s0) * NPG + tb + n0) * 8;
      int g1 = ((b * 8 + s1) * NPG + tb + n1) * 8;
      nh0 = *(const uint4*)&hbhi[g0];
      nh1 = *(const uint4*)&hbhi[g1];
      nl0 = *(const uint4*)&hblo[g0];
      nl1 = *(const uint4*)&hblo[g1];
      if (tid < 64) nsq = 0.5f * sq[gbase + tb + tid];
    }

    int base = cur * 512;                 // chunk units: 512 chunks per buffer
    int cb = gbase + it * 64;
    #pragma unroll
    for (int cg = 0; cg < 4; ++cg) {
      v8s ch0 = *(v8s*)&Bhi[(base + (0 + l4) * 64 + cg * 16 + l15) * 8];
      v8s ch1 = *(v8s*)&Bhi[(base + (4 + l4) * 64 + cg * 16 + l15) * 8];
      v8s cl0 = *(v8s*)&Blo[(base + (0 + l4) * 64 + cg * 16 + l15) * 8];
      v8s cl1 = *(v8s*)&Blo[(base + (4 + l4) * 64 + cg * 16 + l15) * 8];
      v4f accA = {0.f, 0.f, 0.f, 0.f}, accB = {0.f, 0.f, 0.f, 0.f};
      accA = __builtin_amdgcn_mfma_f32_16x16x32_bf16(ch0, ofh[0], accA, 0, 0, 0);
      accB = __builtin_amdgcn_mfma_f32_16x16x32_bf16(ch0, ofl[0], accB, 0, 0, 0);
      accA = __builtin_amdgcn_mfma_f32_16x16x32_bf16(ch1, ofh[1], accA, 0, 0, 0);
      accB = __builtin_amdgcn_mfma_f32_16x16x32_bf16(ch1, ofl[1], accB, 0, 0, 0);
      accB = __builtin_amdgcn_mfma_f32_16x16x32_bf16(cl0, ofh[0], accB, 0, 0, 0);
      accB = __builtin_amdgcn_mfma_f32_16x16x32_bf16(cl1, ofh[1], accB, 0, 0, 0);
      int kb = cg * 16 + l4 * 4;
      float k0 = sqch[cur][kb + 0] - (accA[0] + accB[0]);
      float k1 = sqch[cur][kb + 1] - (accA[1] + accB[1]);
      float k2 = sqch[cur][kb + 2] - (accA[2] + accB[2]);
      float k3 = sqch[cur][kb + 3] - (accA[3] + accB[3]);
      float gmin = fminf(fminf(k0, k1), fminf(k2, k3));
      if (gmin < td[9]) {
        float kk[4] = {k0, k1, k2, k3};
        #pragma unroll
        for (int r = 0; r < 4; ++r) {
          if (kk[r] < td[9]) {
            float cd = kk[r]; int ci = cb + kb + r;
            #pragma unroll
            for (int u = 0; u < 10; ++u) {
              bool bt = cd < td[u];
              float nd = bt ? cd : td[u]; int nc = bt ? ci : ti[u];
              float od = bt ? td[u] : cd; int oc = bt ? ti[u] : ci;
              td[u] = nd; ti[u] = nc; cd = od; ci = oc;
            }
          }
        }
      }
    }

    if (more) {
      int nb_ = (cur ^ 1) * 4096;         // short units: 4096 shorts per buffer
      *(uint4*)&Bhi[nb_ + tid * 8]         = nh0;
      *(uint4*)&Bhi[nb_ + (tid + 256) * 8] = nh1;
      *(uint4*)&Blo[nb_ + tid * 8]         = nl0;
      *(uint4*)&Blo[nb_ + (tid + 256) * 8] = nl1;
      if (tid < 64) sqch[cur ^ 1][tid] = nsq;
    }
    __syncthreads();
    cur ^= 1;
  }

  // dump per-lane lists: row rloc has 4 lists (l4) x 10 entries -> merge scratch in B LDS
  float* mbd = (float*)Bhi;   // 64*4*10*4B = 10240 B, fits in 16 KB
  int*   mbi = (int*)Blo;
  #pragma unroll
  for (int j = 0; j < 10; ++j) {
    mbd[(rloc * 4 + l4) * 10 + j] = td[j];
    mbi[(rloc * 4 + l4) * 10 + j] = ti[j];
  }
  __syncthreads();
  if (tid < 64) {
    int rn = rowbase + tid;
    float fd[12]; int fi[12];
    #pragma unroll
    for (int j = 0; j < 12; ++j) { fd[j] = 1e30f; fi[j] = 0x7fffffff; }
    #pragma unroll 1
    for (int u = 0; u < 40; ++u) {
      float cd = mbd[tid * 40 + u];
      int   ci = mbi[tid * 40 + u];
      if (ci != rn && (cd < fd[11] || (cd == fd[11] && ci < fi[11]))) {
        #pragma unroll
        for (int v = 0; v < 12; ++v) {
          bool better = (cd < fd[v]) || (cd == fd[v] && ci < fi[v]);
          if (better) { float tf = fd[v]; int tq = fi[v]; fd[v] = cd; fi[v] = ci; cd = tf; ci = tq; }
        }
      }
    }
    #pragma unroll
    for (int j = 0; j < 12; ++j) cand[rn * 12 + j] = fi[j];
  }
}

// ---------------- exact fp32 refinement: top-8 of the 12 candidates ----------------
__global__ __launch_bounds__(256) void k_refine(
    const float* __restrict__ h, const int* __restrict__ cand, int* __restrict__ knn) {
  int wv = threadIdx.x >> 6, lane = threadIdx.x & 63;
  int n = blockIdx.x * 4 + wv;
  float hn = h[n * 64 + lane];
  float td[8]; int ti[8];
  #pragma unroll
  for (int j = 0; j < 8; ++j) { td[j] = 1e30f; ti[j] = 0x7fffffff; }
  #pragma unroll 1
  for (int j = 0; j < 12; ++j) {
    int c = cand[n * 12 + j];
    float df = h[c * 64 + lane] - hn;
    float s = df * df;
    #pragma unroll
    for (int d = 32; d > 0; d >>= 1) s += __shfl_xor(s, d, 64);
    if (s < td[7] || (s == td[7] && c < ti[7])) {
      float cd = s; int ci = c;
      #pragma unroll
      for (int u = 0; u < 8; ++u) {
        bool better = (cd < td[u]) || (cd == td[u] && ci < ti[u]);
        if (better) { float tf = td[u]; int tq = ti[u]; td[u] = cd; ti[u] = ci; cd = tf; ci = tq; }
      }
    }
  }
  #pragma unroll
  for (int u = 0; u < 8; ++u) {
    if (lane == u) knn[n * 8 + u] = ti[u];
  }
}

// ---------------- dyn-MLP prep: A = h*W1[0:64] + b1, C = h*W1[64:128]  (per node) ----------------
__global__ __launch_bounds__(256) void k_dynprep(
    const float* __restrict__ h,
    const float* __restrict__ w1, const float* __restrict__ b1,
    float* __restrict__ A, float* __restrict__ C) {
  __shared__ alignas(16) float hT[64 * 20];         // [j][16 nodes], pad 20
  int t = threadIdx.x;
  int nb = blockIdx.x * 16;
  {
    int n = t >> 4, qj = t & 15;
    float4 v = *(const float4*)(h + (nb + n) * 64 + qj * 4);
    hT[(qj * 4 + 0) * 20 + n] = v.x;
    hT[(qj * 4 + 1) * 20 + n] = v.y;
    hT[(qj * 4 + 2) * 20 + n] = v.z;
    hT[(qj * 4 + 3) * 20 + n] = v.w;
  }
  __syncthreads();
  int pq = t >> 6, cq = t & 63;
  int oc = cq * 2;
  const float* wb; float* ob; int ocl; float bv0, bv1;
  if (oc < 64) { wb = w1 + oc;             ob = A; ocl = oc;      bv0 = b1[oc]; bv1 = b1[oc + 1]; }
  else         { wb = w1 + 4096 + (oc-64); ob = C; ocl = oc - 64; bv0 = 0.f;    bv1 = 0.f; }
  float acc[4][2];
  #pragma unroll
  for (int i = 0; i < 4; ++i) { acc[i][0] = bv0; acc[i][1] = bv1; }
  for (int j = 0; j < 64; ++j) {
    float4 av = *(float4*)&hT[j * 20 + pq * 4];
    float2 wv = *(const float2*)(wb + j * 64);
    acc[0][0] += av.x * wv.x; acc[0][1] += av.x * wv.y;
    acc[1][0] += av.y * wv.x; acc[1][1] += av.y * wv.y;
    acc[2][0] += av.z * wv.x; acc[2][1] += av.z * wv.y;
    acc[3][0] += av.w * wv.x; acc[3][1] += av.w * wv.y;
  }
  #pragma unroll
  for (int i = 0; i < 4; ++i) {
    int n = nb + pq * 4 + i;
    ob[n * 64 + ocl]     = acc[i][0];
    ob[n * 64 + ocl + 1] = acc[i][1];
  }
}

// ---------------- dyn-MLP aggregate: ybar = mean_k lrelu(A_n + C_m - C_n); out = ybar*W2 + b2 ----
__global__ __launch_bounds__(256) void k_dynagg(
    const float* __restrict__ A, const float* __restrict__ C,
    const int* __restrict__ knn, const float* __restrict__ w2,
    const float* __restrict__ b2, float* __restrict__ out) {
  __shared__ float w2sh[64 * 64];
  __shared__ float ysh[4 * 64];
  int t = threadIdx.x, wv = t >> 6, lane = t & 63;
  int n = blockIdx.x * 4 + wv;
  for (int u = t; u < 1024; u += 256) *(float4*)&w2sh[u * 4] = *(const float4*)&w2[u * 4];
  float a  = A[n * 64 + lane];
  float cn = C[n * 64 + lane];
  int mm[8];
  #pragma unroll
  for (int k = 0; k < 8; ++k) mm[k] = knn[n * 8 + k];
  float cm[8];
  #pragma unroll
  for (int k = 0; k < 8; ++k) cm[k] = C[mm[k] * 64 + lane];
  float bse = a - cn;
  float s = 0.f;
  #pragma unroll
  for (int k = 0; k < 8; ++k) s += lrelu(bse + cm[k]);
  ysh[wv * 64 + lane] = s * 0.125f;
  __syncthreads();
  float acc = b2[lane];
  for (int j = 0; j < 64; j += 4) {
    float y0 = ysh[wv * 64 + j],     y1 = ysh[wv * 64 + j + 1];
    float y2 = ysh[wv * 64 + j + 2], y3 = ysh[wv * 64 + j + 3];
    acc += y0 * w2sh[j * 64 + lane]       + y1 * w2sh[(j + 1) * 64 + lane]
         + y2 * w2sh[(j + 2) * 64 + lane] + y3 * w2sh[(j + 3) * 64 + lane];
  }
  out[n * 64 + lane] = acc;
}

// ---------------- GAT2 node transforms (in-dim 64, l+r fused) ----------------
__global__ __launch_bounds__(256) void k_xform64(
    const float* __restrict__ h,
    const float* __restrict__ wl, const float* __restrict__ bl,
    const float* __restrict__ wr, const float* __restrict__ br,
    float* __restrict__ xl, float* __restrict__ xr) {
  __shared__ alignas(16) float hT[64 * 20];         // [j][16 nodes], pad 20
  int t = threadIdx.x;
  int nb = blockIdx.x * 16;
  {
    int n = t >> 4, qj = t & 15;
    float4 v = *(const float4*)(h + (nb + n) * 64 + qj * 4);
    hT[(qj * 4 + 0) * 20 + n] = v.x;
    hT[(qj * 4 + 1) * 20 + n] = v.y;
    hT[(qj * 4 + 2) * 20 + n] = v.z;
    hT[(qj * 4 + 3) * 20 + n] = v.w;
  }
  __syncthreads();
  int pq = t >> 6, cq = t & 63;
  int oc = cq * 4;
  const float* wb; const float* bb; float* ob; int ocl;
  if (oc < 128) { wb = wl + oc;         bb = bl + oc;         ob = xl; ocl = oc; }
  else          { wb = wr + (oc - 128); bb = br + (oc - 128); ob = xr; ocl = oc - 128; }
  float acc[4][4];
  #pragma unroll
  for (int c = 0; c < 4; ++c) {
    float bv = bb[c];
    #pragma unroll
    for (int i = 0; i < 4; ++i) acc[i][c] = bv;
  }
  for (int j = 0; j < 64; ++j) {
    float4 av = *(float4*)&hT[j * 20 + pq * 4];
    float4 wv = *(const float4*)(wb + j * 128);
    float aa[4] = {av.x, av.y, av.z, av.w};
    float ww[4] = {wv.x, wv.y, wv.z, wv.w};
    #pragma unroll
    for (int i = 0; i < 4; ++i)
      #pragma unroll
      for (int c = 0; c < 4; ++c) acc[i][c] += aa[i] * ww[c];
  }
  #pragma unroll
  for (int i = 0; i < 4; ++i) {
    int n = nb + pq * 4 + i;
    #pragma unroll
    for (int c = 0; c < 4; ++c) ob[n * 128 + ocl + c] = acc[i][c];
  }
}

// ---------------- per-graph softmax pool + context MLP (fused) ----------------
__global__ __launch_bounds__(1024) void k_pool(
    const float* __restrict__ gates, const float* __restrict__ h3,
    float* __restrict__ pexp,
    const float* __restrict__ cw1, const float* __restrict__ cb1,
    const float* __restrict__ cw2, const float* __restrict__ cb2,
    float* __restrict__ gctx) {
  int b = blockIdx.x, t = threadIdx.x;
  const float* g = gates + b * NPG;
  __shared__ float red[1024];
  __shared__ float gpsh[64], tsh[64];
  float m = -1e30f;
  for (int i = t; i < NPG; i += 1024) m = fmaxf(m, g[i]);
  red[t] = m; __syncthreads();
  for (int s = 512; s > 0; s >>= 1) { if (t < s) red[t] = fmaxf(red[t], red[t + s]); __syncthreads(); }
  m = red[0]; __syncthreads();
  float sum = 0.f;
  for (int i = t; i < NPG; i += 1024) { float p = __expf(g[i] - m); pexp[b * NPG + i] = p; sum += p; }
  red[t] = sum; __syncthreads();
  for (int s = 512; s > 0; s >>= 1) { if (t < s) red[t] += red[t + s]; __syncthreads(); }
  float den = red[0];
  __syncthreads();
  int grp = t >> 6, c = t & 63;
  float acc = 0.f;
  for (int i = grp; i < NPG; i += 16) acc += pexp[b * NPG + i] * h3[(b * NPG + i) * 64 + c];
  red[t] = acc; __syncthreads();
  if (t < 64) {
    float a = 0.f;
    for (int qq = 0; qq < 16; ++qq) a += red[qq * 64 + t];
    gpsh[t] = a / den;
  }
  __syncthreads();
  if (t < 64) {
    float s = cb1[t];
    for (int j = 0; j < 64; ++j) s += gpsh[j] * cw1[j * 64 + t];
    tsh[t] = lrelu(s);
  }
  __syncthreads();
  if (t < 64) {
    float o = cb2[t];
    for (int j = 0; j < 64; ++j) o += tsh[j] * cw2[j * 64 + t];
    gctx[b * 64 + t] = o;
  }
}

// ---------------- fused decoder: 133->128 -> LN -> 64 -> 3, +x, tanh*CAP ----------------
__global__ __launch_bounds__(128) void k_decoder(
    const float* __restrict__ h3, const float* __restrict__ gctx, const float* __restrict__ x,
    const float* __restrict__ w1, const float* __restrict__ b1,
    const float* __restrict__ lng, const float* __restrict__ lnb,
    const float* __restrict__ w2, const float* __restrict__ b2,
    const float* __restrict__ w3, const float* __restrict__ b3,
    float* __restrict__ out) {
  __shared__ alignas(16) float hf[16 * 136];
  __shared__ alignas(16) float dT[16 * 132];
  __shared__ float d2[16 * 65];
  __shared__ float mu[16], rs[16];
  int t = threadIdx.x;
  int nb = blockIdx.x * 16;
  int gb = nb >> 12;
  for (int u = t; u < 16 * 64; u += 128) { int p = u >> 6, j = u & 63; hf[p * 136 + j] = h3[(nb + p) * 64 + j]; }
  for (int u = t; u < 16 * 64; u += 128) { int p = u >> 6, j = u & 63; hf[p * 136 + 64 + j] = gctx[gb * 64 + j]; }
  for (int u = t; u < 16 * 5; u += 128) { int p = u / 5, j = u % 5; hf[p * 136 + 128 + j] = x[(nb + p) * 5 + j]; }
  __syncthreads();
  float acc[16];
  #pragma unroll
  for (int p = 0; p < 16; ++p) acc[p] = b1[t];
  for (int j4 = 0; j4 < 128; j4 += 4) {
    float w0 = w1[(j4 + 0) * 128 + t], wv1 = w1[(j4 + 1) * 128 + t];
    float wv2 = w1[(j4 + 2) * 128 + t], wv3 = w1[(j4 + 3) * 128 + t];
    #pragma unroll
    for (int p = 0; p < 16; ++p) {
      float4 hv = *(float4*)&hf[p * 136 + j4];
      acc[p] += hv.x * w0 + hv.y * wv1 + hv.z * wv2 + hv.w * wv3;
    }
  }
  for (int j = 128; j < 133; ++j) {
    float w = w1[j * 128 + t];
    #pragma unroll
    for (int p = 0; p < 16; ++p) acc[p] += hf[p * 136 + j] * w;
  }
  #pragma unroll
  for (int p = 0; p < 16; ++p) dT[p * 132 + t] = lrelu(acc[p]);
  __syncthreads();
  if (t < 16) {
    float s = 0.f, s2 = 0.f;
    for (int j = 0; j < 128; ++j) { float v = dT[t * 132 + j]; s += v; s2 += v * v; }
    float mn = s * (1.f / 128.f);
    float vr = s2 * (1.f / 128.f) - mn * mn;
    mu[t] = mn; rs[t] = rsqrtf(vr + 1e-5f);
  }
  __syncthreads();
  float lg = lng[t], lb = lnb[t];
  #pragma unroll
  for (int p = 0; p < 16; ++p) dT[p * 132 + t] = (dT[p * 132 + t] - mu[p]) * rs[p] * lg + lb;
  __syncthreads();
  if (t < 64) {
    float a2[16];
    #pragma unroll
    for (int p = 0; p < 16; ++p) a2[p] = b2[t];
    for (int j4 = 0; j4 < 128; j4 += 4) {
      float w0 = w2[(j4 + 0) * 64 + t], wv1 = w2[(j4 + 1) * 64 + t];
      float wv2 = w2[(j4 + 2) * 64 + t], wv3 = w2[(j4 + 3) * 64 + t];
      #pragma unroll
      for (int p = 0; p < 16; ++p) {
        float4 dv = *(float4*)&dT[p * 132 + j4];
        a2[p] += dv.x * w0 + dv.y * wv1 + dv.z * wv2 + dv.w * wv3;
      }
    }
    #pragma unroll
    for (int p = 0; p < 16; ++p) d2[p * 65 + t] = lrelu(a2[p]);
  }
  __syncthreads();
  if (t < 48) {
    int p = t / 3, k = t % 3;
    float o = b3[k];
    for (int j = 0; j < 64; ++j) o += d2[p * 65 + j] * w3[j * 3 + k];
    out[(nb + p) * 3 + k] = x[(nb + p) * 5 + k] + tanhf(o) * 20.0f;
  }
}

// ---------------- workspace layout (bytes) ----------------
#define O_XL     0ul
#define O_HBHI   0ul
#define O_A      0ul           // 8 MB, after gram_topk (hbhi/hblo dead)
#define O_HBLO   4194304ul
#define O_SQ     8388608ul
#define O_KNN    8519680ul
#define O_XR     16777216ul
#define O_CAND   16777216ul
#define O_C      16777216ul    // 8 MB
#define O_H1     33554432ul    // 8 MB: GAT1 out -> h1 -> (GAT2 out -> h3)
#define O_H2     41943040ul    // 8 MB: dynagg out -> h2
#define O_CNT    50331648ul
#define O_START  50462720ul
#define O_CUR    50593792ul
#define O_BKT    50724864ul    // edge ids by bucket order (2 MB)
#define O_BSRC   52822016ul    // src node  by bucket order (2 MB)
#define O_STAT   54919168ul
#define O_GATES  54920192ul
#define O_PEXP   55051264ul
#define O_GCTX   55184384ul

extern "C" void kernel_launch(void* const* d_in, const int* in_sizes, int n_in,
                              void* d_out, int out_size, void* d_ws, size_t ws_size,
                              hipStream_t stream) {
  (void)in_sizes; (void)n_in; (void)out_size; (void)ws_size;
  const float* x      = (const float*)d_in[0];
  const float* eattr  = (const float*)d_in[1];
  const int*   ei     = (const int*)d_in[2];
  const float* g1_wl  = (const float*)d_in[3];
  const float* g1_bl  = (const float*)d_in[4];
  const float* g1_wr  = (const float*)d_in[5];
  const float* g1_br  = (const float*)d_in[6];
  const float* g1_we  = (const float*)d_in[7];
  const float* g1_att = (const float*)d_in[8];
  const float* g1_bias= (const float*)d_in[9];
  const float* bn1_g  = (const float*)d_in[10];
  const float* bn1_b  = (const float*)d_in[11];
  const float* em_w1  = (const float*)d_in[12];
  const float* em_b1  = (const float*)d_in[13];
  const float* em_w2  = (const float*)d_in[14];
  const float* em_b2  = (const float*)d_in[15];
  const float* bn2_g  = (const float*)d_in[16];
  const float* bn2_b  = (const float*)d_in[17];
  const float* g2_wl  = (const float*)d_in[18];
  const float* g2_bl  = (const float*)d_in[19];
  const float* g2_wr  = (const float*)d_in[20];
  const float* g2_br  = (const float*)d_in[21];
  const float* g2_att = (const float*)d_in[22];
  const float* g2_bias= (const float*)d_in[23];
  const float* bn3_g  = (const float*)d_in[24];
  const float* bn3_b  = (const float*)d_in[25];
  const float* gt_w1  = (const float*)d_in[26];
  const float* gt_b1  = (const float*)d_in[27];
  const float* gt_w2  = (const float*)d_in[28];
  const float* gt_b2  = (const float*)d_in[29];
  const float* cx_w1  = (const float*)d_in[30];
  const float* cx_b1  = (const float*)d_in[31];
  const float* cx_w2  = (const float*)d_in[32];
  const float* cx_b2  = (const float*)d_in[33];
  const float* dc_w1  = (const float*)d_in[34];
  const float* dc_b1  = (const float*)d_in[35];
  const float* ln_g   = (const float*)d_in[36];
  const float* ln_b   = (const float*)d_in[37];
  const float* dc_w2  = (const float*)d_in[38];
  const float* dc_b2  = (const float*)d_in[39];
  const float* dc_w3  = (const float*)d_in[40];
  const float* dc_b3  = (const float*)d_in[41];

  char* ws = (char*)d_ws;
  float* xl    = (float*)(ws + O_XL);
  float* xr    = (float*)(ws + O_XR);
  float* h1    = (float*)(ws + O_H1);
  float* h2    = (float*)(ws + O_H2);
  int*   cnt   = (int*)(ws + O_CNT);
  int*   start = (int*)(ws + O_START);
  int*   cur   = (int*)(ws + O_CUR);
  int*   bkt   = (int*)(ws + O_BKT);
  int*   bsrc  = (int*)(ws + O_BSRC);
  unsigned short* hbhi = (unsigned short*)(ws + O_HBHI);
  unsigned short* hblo = (unsigned short*)(ws + O_HBLO);
  float* sq    = (float*)(ws + O_SQ);
  int*   knn   = (int*)(ws + O_KNN);
  int*   cand  = (int*)(ws + O_CAND);
  float* Aar   = (float*)(ws + O_A);
  float* Car   = (float*)(ws + O_C);
  float* stat  = (float*)(ws + O_STAT);
  float* gates = (float*)(ws + O_GATES);
  float* pexp  = (float*)(ws + O_PEXP);
  float* gctx  = (float*)(ws + O_GCTX);

  const int* src = ei;
  const int* dst = ei + NE;

  // ---- GAT layer 1 ----
  hipMemsetAsync(cnt, 0, NN * 4, stream);
  k_xform5<<<NN * 128 / 256, 256, 0, stream>>>(x, g1_wl, g1_bl, g1_wr, g1_br, xl, xr);
  k_count<<<NE / 256, 256, 0, stream>>>(dst, cnt);
  k_scan<<<1, 1024, 0, stream>>>(cnt, start, cur);
  k_scatter<<<NE / 256, 256, 0, stream>>>(dst, src, cur, bkt, bsrc);
  k_gat_edge<1><<<NN / 4, 256, 0, stream>>>(xl, xr, eattr, g1_we, g1_att, g1_bias,
                                            start, cnt, bsrc, bkt, h1);
  hipMemsetAsync(stat, 0, 512, stream);
  k_bn_reduce<<<256, 256, 0, stream>>>(h1, stat);
  k_bn_apply_split<<<NN / 4, 256, 0, stream>>>(h1, stat, bn1_g, bn1_b, hbhi, hblo, sq);

  // ---- dynamic kNN (approx MFMA gram + exact fp32 refine) + separable edge MLP ----
  k_gram_topk<<<NGR * (NPG / 64), 256, 0, stream>>>(hbhi, hblo, sq, cand);
  k_refine<<<NN / 4, 256, 0, stream>>>(h1, cand, knn);
  k_dynprep<<<NN / 16, 256, 0, stream>>>(h1, em_w1, em_b1, Aar, Car);
  k_dynagg<<<NN / 4, 256, 0, stream>>>(Aar, Car, knn, em_w2, em_b2, h2);
  hipMemsetAsync(stat, 0, 512, stream);
  k_bn_reduce<<<256, 256, 0, stream>>>(h2, stat);
  k_bn_applyf<<<NN * 64 / 256, 256, 0, stream>>>(h2, stat, bn2_g, bn2_b);

  // ---- GAT layer 2 ----
  k_xform64<<<NN / 16, 256, 0, stream>>>(h2, g2_wl, g2_bl, g2_wr, g2_br, xl, xr);
  k_gat_edge<0><<<NN / 4, 256, 0, stream>>>(xl, xr, nullptr, nullptr, g2_att, g2_bias,
                                            start, cnt, bsrc, bkt, h1);
  hipMemsetAsync(stat, 0, 512, stream);
  k_bn_reduce<<<256, 256, 0, stream>>>(h1, stat);
  k_bn_apply_gate<<<NN / 4, 256, 0, stream>>>(h1, stat, bn3_g, bn3_b,
                                              gt_w1, gt_b1, gt_w2, gt_b2, gates);

  // ---- pooling + context (fused) ----
  k_pool<<<NGR, 1024, 0, stream>>>(gates, h1, pexp, cx_w1, cx_b1, cx_w2, cx_b2, gctx);

  // ---- decoder ----
  k_decoder<<<NN / 16, 128, 0, stream>>>(h1, gctx, x, dc_w1, dc_b1, ln_g, ln_b,
                                         dc_w2, dc_b2, dc_w3, dc_b3, (float*)d_out);
}